// Round 2
// 477.531 us; speedup vs baseline: 1.4099x; 1.4099x over previous
//
#include <hip/hip_runtime.h>
#include <stdint.h>

// ---------------------------------------------------------------------------
// Predictor: MLP (256->512->256->128) -> LSTM(128 in, 256 hidden, T=50)
//   - MLP via split-bf16 (hi+lo) MFMA gemms, lgkm-only barriers + tile
//     prefetch so global latency overlaps MFMA.
//   - LSTM v2: 256 blocks x 512 thr (ALL 256 CUs), M=16 rows/block, 50 steps
//     in-kernel. W_hh bf16 fragments streamed from L2 with a PERSISTENT
//     2-kt-DEEP rolling register prefetch (issue-to-use ~2 kt ~ 320 cyc >=
//     L2 latency; loads stay ahead of output stores in the vmcnt FIFO).
//     W_hh repacked so a wave's 8 frags per kt are contiguous (base+imm
//     addressing). h double-buffered in LDS in A-fragment layout with a
//     depth-1 rolling ds_read prefetch; c-state in VGPRs. lgkm-only step
//     barrier; plain (L2-ack) output stores.
//   (Resubmission: round-1 bench died to container-level infra failure; no
//    kernel-level evidence of a fault. Source unchanged from v2.)
// ---------------------------------------------------------------------------

typedef short short8 __attribute__((ext_vector_type(8)));
typedef float floatx4 __attribute__((ext_vector_type(4)));
typedef unsigned short ushort4v __attribute__((ext_vector_type(4)));

#define BATCH 4096
#define HID 256
#define TSTEPS 50

static __device__ __forceinline__ unsigned short f2bf(float x) {
  union { float f; unsigned int u; } v; v.f = x;
  unsigned int r = (v.u + 0x7fffu + ((v.u >> 16) & 1u)) >> 16;  // RNE
  return (unsigned short)r;
}
static __device__ __forceinline__ float bf2f(unsigned short h) {
  union { unsigned int u; float f; } v; v.u = ((unsigned int)h) << 16;
  return v.f;
}
static __device__ __forceinline__ float sigmf(float x) {
  return __builtin_amdgcn_rcpf(1.0f + __expf(-x));
}
static __device__ __forceinline__ float tanhf_(float x) {
  return 1.0f - 2.0f * __builtin_amdgcn_rcpf(__expf(2.0f * x) + 1.0f);
}

// lgkm-only barrier: LDS visibility without draining the vmcnt queue.
static __device__ __forceinline__ void lds_barrier() {
  __asm__ volatile("s_waitcnt lgkmcnt(0)\n\ts_barrier" ::: "memory");
}

// ---------------------------------------------------------------------------
// Fused fp32 -> (hi,lo) bf16 split for all 5 arrays in one launch.
// Work item = one float4. Segment boundaries (in float4 units) hard-coded.
// ---------------------------------------------------------------------------
__global__ __launch_bounds__(256) void split_all(
    const float* __restrict__ s0, unsigned short* __restrict__ h0, unsigned short* __restrict__ l0,
    const float* __restrict__ s1, unsigned short* __restrict__ h1, unsigned short* __restrict__ l1,
    const float* __restrict__ s2, unsigned short* __restrict__ h2, unsigned short* __restrict__ l2,
    const float* __restrict__ s3, unsigned short* __restrict__ h3, unsigned short* __restrict__ l3,
    const float* __restrict__ s4, unsigned short* __restrict__ h4, unsigned short* __restrict__ l4) {
  int i = blockIdx.x * 256 + threadIdx.x;
  const float* src; unsigned short *dh, *dl; int off;
  if (i < 262144)      { src = s0; dh = h0; dl = l0; off = i; }
  else if (i < 294912) { src = s1; dh = h1; dl = l1; off = i - 262144; }
  else if (i < 327680) { src = s2; dh = h2; dl = l2; off = i - 294912; }
  else if (i < 335872) { src = s3; dh = h3; dl = l3; off = i - 327680; }
  else if (i < 368640) { src = s4; dh = h4; dl = l4; off = i - 335872; }
  else return;
  float4 v = ((const float4*)src)[off];
  float cc[4] = {v.x, v.y, v.z, v.w};
  ushort4v h, l;
#pragma unroll
  for (int j = 0; j < 4; ++j) {
    unsigned short hb = f2bf(cc[j]);
    h[j] = hb;
    l[j] = f2bf(cc[j] - bf2f(hb));
  }
  ((ushort4v*)dh)[off] = h;
  ((ushort4v*)dl)[off] = l;
}

// ---------------------------------------------------------------------------
// Split-bf16 MFMA GEMM: C = act(A @ B^T + bias (+bias2)), A:[M,K], B:[N,K]
// hi/lo bf16 pairs, row-major. 64x64 tile, 256 thr, BK=32, XOR-swizzled LDS.
// Pipelined: next k-tile's global loads issue before this tile's MFMAs;
// lgkm-only barriers keep the vmcnt queue flowing.
// ---------------------------------------------------------------------------
template <int RELU, int OUT_SPLIT, int HAS_B2>
__global__ __launch_bounds__(256) void gemm_df(
    const unsigned short* __restrict__ Ah, const unsigned short* __restrict__ Al,
    const unsigned short* __restrict__ Bh, const unsigned short* __restrict__ Bl,
    const float* __restrict__ bias, const float* __restrict__ bias2,
    float* __restrict__ Cf, unsigned short* __restrict__ Ch,
    unsigned short* __restrict__ Cl, int M, int N, int K) {
  __shared__ unsigned short Ash[64 * 32], Asl[64 * 32];
  __shared__ unsigned short Bsh[64 * 32], Bsl[64 * 32];
  const int tid = threadIdx.x;
  const int wave = tid >> 6, lane = tid & 63;
  const int quad = lane >> 4, l16 = lane & 15;
  const int bm = blockIdx.y * 64, bn = blockIdx.x * 64;
  const int lr = tid >> 2, lc = tid & 3;
  const int wofs = lr * 32 + ((lc ^ (lr & 3)) * 8);  // swizzled 16B chunk

  floatx4 acc[4] = {};
  // preload k-tile 0
  short8 avh = *(const short8*)(Ah + (size_t)(bm + lr) * K + lc * 8);
  short8 avl = *(const short8*)(Al + (size_t)(bm + lr) * K + lc * 8);
  short8 bvh = *(const short8*)(Bh + (size_t)(bn + lr) * K + lc * 8);
  short8 bvl = *(const short8*)(Bl + (size_t)(bn + lr) * K + lc * 8);

  for (int k0 = 0; k0 < K; k0 += 32) {
    lds_barrier();  // prior tile's LDS reads complete
    *(short8*)&Ash[wofs] = avh;
    *(short8*)&Asl[wofs] = avl;
    *(short8*)&Bsh[wofs] = bvh;
    *(short8*)&Bsl[wofs] = bvl;
    lds_barrier();
    if (k0 + 32 < K) {  // issue next tile's loads; MFMAs below hide latency
      avh = *(const short8*)(Ah + (size_t)(bm + lr) * K + k0 + 32 + lc * 8);
      avl = *(const short8*)(Al + (size_t)(bm + lr) * K + k0 + 32 + lc * 8);
      bvh = *(const short8*)(Bh + (size_t)(bn + lr) * K + k0 + 32 + lc * 8);
      bvl = *(const short8*)(Bl + (size_t)(bn + lr) * K + k0 + 32 + lc * 8);
    }
    const int bro = (wave * 16 + l16) * 32 + ((quad ^ (l16 & 3)) * 8);
    short8 bh = *(const short8*)&Bsh[bro];
    short8 bl = *(const short8*)&Bsl[bro];
#pragma unroll
    for (int i = 0; i < 4; ++i) {
      const int aro = (i * 16 + l16) * 32 + ((quad ^ (l16 & 3)) * 8);
      short8 ah = *(const short8*)&Ash[aro];
      short8 al = *(const short8*)&Asl[aro];
      acc[i] = __builtin_amdgcn_mfma_f32_16x16x32_bf16(al, bh, acc[i], 0, 0, 0);
      acc[i] = __builtin_amdgcn_mfma_f32_16x16x32_bf16(ah, bl, acc[i], 0, 0, 0);
      acc[i] = __builtin_amdgcn_mfma_f32_16x16x32_bf16(ah, bh, acc[i], 0, 0, 0);
    }
  }
  const int col = bn + wave * 16 + l16;
  float bj = bias[col];
  if (HAS_B2) bj += bias2[col];
#pragma unroll
  for (int i = 0; i < 4; ++i)
#pragma unroll
    for (int r = 0; r < 4; ++r) {
      int row = bm + i * 16 + quad * 4 + r;
      float v = acc[i][r] + bj;
      if (RELU) v = fmaxf(v, 0.f);
      if (OUT_SPLIT) {
        unsigned short hb = f2bf(v);
        Ch[(size_t)row * N + col] = hb;
        Cl[(size_t)row * N + col] = f2bf(v - bf2f(hb));
      } else {
        Cf[(size_t)row * N + col] = v;
      }
    }
}

// ---------------------------------------------------------------------------
// Pack W_hh [1024,256] fp32 -> bf16 B-fragment layout, wave-contiguous:
//   idx = ((kt*8 + w)*8 + i)*64 + lane, nt = (i>>1)*16 + w*2 + (i&1)
//   frag content: lane holds B[n = nt*16 + (lane&15)][kt*32 + (lane>>4)*8 + j]
// Per (kt, wave) the 8 fragments are contiguous 8 KB -> base + imm offsets.
// ---------------------------------------------------------------------------
__global__ __launch_bounds__(256) void pack_whh(const float* __restrict__ W,
                                                unsigned short* __restrict__ o) {
  int idx = blockIdx.x * 256 + threadIdx.x;  // ((kt*8+w)*8+i)*64 + lane
  int lane = idx & 63;
  int i = (idx >> 6) & 7;
  int w = (idx >> 9) & 7;
  int kt = idx >> 12;
  int nt = (i >> 1) * 16 + w * 2 + (i & 1);
  int n = nt * 16 + (lane & 15);
  int k0 = kt * 32 + (lane >> 4) * 8;
  const float* src = W + (size_t)n * 256 + k0;
  unsigned short* dst = o + (size_t)idx * 8;
#pragma unroll
  for (int j = 0; j < 8; ++j) dst[j] = f2bf(src[j]);
}

// ---------------------------------------------------------------------------
// Persistent LSTM: 256 blocks x 512 threads (8 waves). Block owns 16 batch
// rows for all 50 steps -> all 256 CUs active. Wave w: u-tiles {2w,2w+1} x
// 4 gates. Rolling 2-kt-deep B prefetch persists ACROSS steps (kt=6/7 of
// step t issue kt'=0/1 of step t+1, ahead of the output stores in the vmcnt
// FIFO -> no store-drain on the critical path, L2 latency fully covered).
// ---------------------------------------------------------------------------
__global__ __launch_bounds__(512, 2) void lstm_kernel(
    const float* __restrict__ xp,            // [4096,1024] fp32, gates i|f|g|o
    const unsigned short* __restrict__ whhf, // packed bf16 fragments
    float* __restrict__ out) {               // [4096,50,256] fp32
  __shared__ unsigned short h_frag[2][8][64][8];  // [buf][kt][lane][j]

  const int tid = threadIdx.x;
  const int wave = tid >> 6;
  const int lane = tid & 63;
  const int quad = lane >> 4;
  const int l16 = lane & 15;
  const int block_m = blockIdx.x * 16;
  const int ut0 = wave * 2;

  for (int i = tid; i < 2 * 8 * 64 * 8; i += 512)
    ((unsigned short*)h_frag)[i] = 0;

  // x_part in registers, C-fragment layout; i = g*2 + utl
  floatx4 xpreg[8];
#pragma unroll
  for (int i = 0; i < 8; ++i) {
    int g = i >> 1, utl = i & 1;
    int col = g * 256 + (ut0 + utl) * 16 + l16;
    floatx4 v;
#pragma unroll
    for (int r = 0; r < 4; ++r)
      v[r] = xp[(size_t)(block_m + quad * 4 + r) * 1024 + col];
    xpreg[i] = v;
  }

  float c[2][4] = {};

  // Persistent rolling B-fragment pipeline, 2 kt-tiles deep (lives across
  // timesteps). Buffer id = kt & 3; 8 kt % 4 == 0 so the cycle is clean
  // across the step boundary.
  short8 bbuf[4][8];
#pragma unroll
  for (int kt = 0; kt < 2; ++kt) {
    const unsigned short* wb0 =
        whhf + ((size_t)((kt * 8 + wave) * 8) * 64 + lane) * 8;
#pragma unroll
    for (int i = 0; i < 8; ++i)
      bbuf[kt][i] = *(const short8*)(wb0 + i * 512);
  }

  __syncthreads();

  const size_t orow = (size_t)TSTEPS * HID;
  int cur = 0;

#pragma unroll 1
  for (int t = 0; t < TSTEPS; ++t) {
    // launder: keep B loads inside the loop (no LICM -> no full-reg hoist)
    const unsigned short* wb = whhf;
    asm volatile("" : "+s"(wb));

    floatx4 acc[8];
#pragma unroll
    for (int i = 0; i < 8; ++i) acc[i] = xpreg[i];

    // rolling A-fragment (h) prefetch, depth 1, within-step only
    short8 aab[2];
    aab[0] = *(const short8*)&h_frag[cur][0][lane][0];

#pragma unroll
    for (int kt = 0; kt < 8; ++kt) {
      // Unconditional rolling prefetch 2 kt ahead: kt=6/7 fetch next step's
      // kt'=0/1 (t-invariant addresses), issued BEFORE this step's stores.
      const int ktn = (kt + 2) & 7;
      const unsigned short* wbp =
          wb + ((size_t)((ktn * 8 + wave) * 8) * 64 + lane) * 8;
#pragma unroll
      for (int i = 0; i < 8; ++i)
        bbuf[(kt + 2) & 3][i] = *(const short8*)(wbp + i * 512);

      if (kt < 7)  // next A-frag from LDS (cur buffer fully written)
        aab[(kt + 1) & 1] = *(const short8*)&h_frag[cur][kt + 1][lane][0];

#pragma unroll
      for (int i = 0; i < 8; ++i)
        acc[i] = __builtin_amdgcn_mfma_f32_16x16x32_bf16(
            aab[kt & 1], bbuf[kt & 3][i], acc[i], 0, 0, 0);
    }

    const int nxt = cur ^ 1;
#pragma unroll
    for (int utl = 0; utl < 2; ++utl) {
      floatx4 gi = acc[0 + utl];
      floatx4 gf = acc[2 + utl];
      floatx4 gg = acc[4 + utl];
      floatx4 go = acc[6 + utl];
      const int u = (ut0 + utl) * 16 + l16;
      const int kt2 = u >> 5;
      const int lhi = ((u >> 3) & 3) << 4;
      const int j2 = u & 7;
#pragma unroll
      for (int r = 0; r < 4; ++r) {
        float iv = sigmf(gi[r]);
        float fv = sigmf(gf[r]);
        float gv = tanhf_(gg[r]);
        float ov = sigmf(go[r]);
        float cv = fmaf(fv, c[utl][r], iv * gv);
        c[utl][r] = cv;
        float hv = ov * tanhf_(cv);
        int mloc = quad * 4 + r;
        // plain store: retires at L2 ack, not HBM
        out[(size_t)(block_m + mloc) * orow + (size_t)t * HID + u] = hv;
        h_frag[nxt][kt2][mloc | lhi][j2] = f2bf(hv);
      }
    }
    cur = nxt;
    lds_barrier();  // h_frag visibility only; vmcnt queue keeps flowing
  }
}

// ---------------------------------------------------------------------------
extern "C" void kernel_launch(void* const* d_in, const int* in_sizes, int n_in,
                              void* d_out, int out_size, void* d_ws, size_t ws_size,
                              hipStream_t stream) {
  const float* zs  = (const float*)d_in[0];
  const float* W1  = (const float*)d_in[1];
  const float* b1  = (const float*)d_in[2];
  const float* W2  = (const float*)d_in[3];
  const float* b2  = (const float*)d_in[4];
  const float* W3  = (const float*)d_in[5];
  const float* b3  = (const float*)d_in[6];
  const float* Wih = (const float*)d_in[7];
  const float* Whh = (const float*)d_in[8];
  const float* bih = (const float*)d_in[9];
  const float* bhh = (const float*)d_in[10];
  float* out = (float*)d_out;

  char* ws = (char*)d_ws;
  const size_t MB = 1024 * 1024;
  unsigned short* zs_h = (unsigned short*)(ws + 0 * MB);       // 2 MB
  unsigned short* zs_l = (unsigned short*)(ws + 2 * MB);       // 2 MB
  unsigned short* h1_h = (unsigned short*)(ws + 4 * MB);       // 4 MB
  unsigned short* h1_l = (unsigned short*)(ws + 8 * MB);       // 4 MB
  unsigned short* h2_h = (unsigned short*)(ws + 0 * MB);       // reuse zs (2 MB)
  unsigned short* h2_l = (unsigned short*)(ws + 2 * MB);       // reuse zs (2 MB)
  unsigned short* zb_h = (unsigned short*)(ws + 12 * MB);      // 1 MB
  unsigned short* zb_l = (unsigned short*)(ws + 13 * MB);      // 1 MB
  unsigned short* w1_h = (unsigned short*)(ws + 14 * MB);                 // 256 KB
  unsigned short* w1_l = (unsigned short*)(ws + 14 * MB + 256 * 1024);
  unsigned short* w2_h = (unsigned short*)(ws + 14 * MB + 512 * 1024);
  unsigned short* w2_l = (unsigned short*)(ws + 14 * MB + 768 * 1024);
  unsigned short* w3_h = (unsigned short*)(ws + 15 * MB);                 // 64 KB
  unsigned short* w3_l = (unsigned short*)(ws + 15 * MB + 64 * 1024);
  unsigned short* wi_h = (unsigned short*)(ws + 15 * MB + 128 * 1024);    // 256 KB
  unsigned short* wi_l = (unsigned short*)(ws + 15 * MB + 384 * 1024);
  float* xp            = (float*)(ws + 16 * MB);               // 16 MB
  unsigned short* whhf = (unsigned short*)(ws + 32 * MB);      // 512 KB

  // fp32 -> hi/lo bf16 splits, one fused launch (zs, W1, W2, W3, Wih)
  split_all<<<1440, 256, 0, stream>>>(zs, zs_h, zs_l, W1, w1_h, w1_l,
                                      W2, w2_h, w2_l, W3, w3_h, w3_l,
                                      Wih, wi_h, wi_l);

  // MLP: h1 = relu(zs@W1^T+b1); h2 = relu(h1@W2^T+b2); zb = h2@W3^T+b3
  gemm_df<1, 1, 0><<<dim3(512 / 64, BATCH / 64), 256, 0, stream>>>(
      zs_h, zs_l, w1_h, w1_l, b1, nullptr, nullptr, h1_h, h1_l, BATCH, 512, 256);
  gemm_df<1, 1, 0><<<dim3(256 / 64, BATCH / 64), 256, 0, stream>>>(
      h1_h, h1_l, w2_h, w2_l, b2, nullptr, nullptr, h2_h, h2_l, BATCH, 256, 512);
  gemm_df<0, 1, 0><<<dim3(128 / 64, BATCH / 64), 256, 0, stream>>>(
      h2_h, h2_l, w3_h, w3_l, b3, nullptr, nullptr, zb_h, zb_l, BATCH, 128, 256);
  // xp = zb@Wih^T + b_ih + b_hh  (fp32 out)
  gemm_df<0, 0, 1><<<dim3(1024 / 64, BATCH / 64), 256, 0, stream>>>(
      zb_h, zb_l, wi_h, wi_l, bih, bhh, xp, nullptr, nullptr, BATCH, 1024, 128);

  pack_whh<<<128, 256, 0, stream>>>(Whh, whhf);

  lstm_kernel<<<BATCH / 16, 512, 0, stream>>>(xp, whhf, out);
}

// Round 3
// 450.601 us; speedup vs baseline: 1.4941x; 1.0598x over previous
//
#include <hip/hip_runtime.h>
#include <stdint.h>

// ---------------------------------------------------------------------------
// Predictor: MLP (256->512->256->128) -> LSTM(128 in, 256 hidden, T=50)
//   - MLP via split-bf16 (hi+lo) MFMA gemms, lgkm-only barriers + tile
//     prefetch so global latency overlaps MFMA.
//   - LSTM v3: 256 blocks x 512 thr, M=16 rows/block, 50 steps in-kernel.
//     The kernel is L2-BW-bound on the W_hh fragment stream (512 KB/CU/step
//     at ~56 B/cyc/CU = 67% of the measured step). v3 cuts that stream 25%:
//     kt-slices 6,7 (128 KB) are cached in LDS once and read via
//     conflict-free ds_read_b128; slices 0..5 stream from L2 via a rolling
//     register pipeline whose issues at kt=6,7 cross the step barrier
//     (tgt 0',1' of step t+1) so the L2 pipe never idles. acc-init is fused
//     into the kt=0 MFMA (C=xpreg). Output stores are non-temporal so the
//     205 MB write stream doesn't evict the streamed W_hh slices from L2.
// ---------------------------------------------------------------------------

typedef short short8 __attribute__((ext_vector_type(8)));
typedef float floatx4 __attribute__((ext_vector_type(4)));
typedef unsigned short ushort4v __attribute__((ext_vector_type(4)));

#define BATCH 4096
#define HID 256
#define TSTEPS 50

static __device__ __forceinline__ unsigned short f2bf(float x) {
  union { float f; unsigned int u; } v; v.f = x;
  unsigned int r = (v.u + 0x7fffu + ((v.u >> 16) & 1u)) >> 16;  // RNE
  return (unsigned short)r;
}
static __device__ __forceinline__ float bf2f(unsigned short h) {
  union { unsigned int u; float f; } v; v.u = ((unsigned int)h) << 16;
  return v.f;
}
static __device__ __forceinline__ float sigmf(float x) {
  return __builtin_amdgcn_rcpf(1.0f + __expf(-x));
}
static __device__ __forceinline__ float tanhf_(float x) {
  return 1.0f - 2.0f * __builtin_amdgcn_rcpf(__expf(2.0f * x) + 1.0f);
}

// lgkm-only barrier: LDS visibility without draining the vmcnt queue.
static __device__ __forceinline__ void lds_barrier() {
  __asm__ volatile("s_waitcnt lgkmcnt(0)\n\ts_barrier" ::: "memory");
}

// ---------------------------------------------------------------------------
// Fused fp32 -> (hi,lo) bf16 split for all 5 arrays in one launch.
// Work item = one float4. Segment boundaries (in float4 units) hard-coded.
// ---------------------------------------------------------------------------
__global__ __launch_bounds__(256) void split_all(
    const float* __restrict__ s0, unsigned short* __restrict__ h0, unsigned short* __restrict__ l0,
    const float* __restrict__ s1, unsigned short* __restrict__ h1, unsigned short* __restrict__ l1,
    const float* __restrict__ s2, unsigned short* __restrict__ h2, unsigned short* __restrict__ l2,
    const float* __restrict__ s3, unsigned short* __restrict__ h3, unsigned short* __restrict__ l3,
    const float* __restrict__ s4, unsigned short* __restrict__ h4, unsigned short* __restrict__ l4) {
  int i = blockIdx.x * 256 + threadIdx.x;
  const float* src; unsigned short *dh, *dl; int off;
  if (i < 262144)      { src = s0; dh = h0; dl = l0; off = i; }
  else if (i < 294912) { src = s1; dh = h1; dl = l1; off = i - 262144; }
  else if (i < 327680) { src = s2; dh = h2; dl = l2; off = i - 294912; }
  else if (i < 335872) { src = s3; dh = h3; dl = l3; off = i - 327680; }
  else if (i < 368640) { src = s4; dh = h4; dl = l4; off = i - 335872; }
  else return;
  float4 v = ((const float4*)src)[off];
  float cc[4] = {v.x, v.y, v.z, v.w};
  ushort4v h, l;
#pragma unroll
  for (int j = 0; j < 4; ++j) {
    unsigned short hb = f2bf(cc[j]);
    h[j] = hb;
    l[j] = f2bf(cc[j] - bf2f(hb));
  }
  ((ushort4v*)dh)[off] = h;
  ((ushort4v*)dl)[off] = l;
}

// ---------------------------------------------------------------------------
// Split-bf16 MFMA GEMM: C = act(A @ B^T + bias (+bias2)), A:[M,K], B:[N,K]
// hi/lo bf16 pairs, row-major. 64x64 tile, 256 thr, BK=32, XOR-swizzled LDS.
// Pipelined: next k-tile's global loads issue before this tile's MFMAs;
// lgkm-only barriers keep the vmcnt queue flowing.
// ---------------------------------------------------------------------------
template <int RELU, int OUT_SPLIT, int HAS_B2>
__global__ __launch_bounds__(256) void gemm_df(
    const unsigned short* __restrict__ Ah, const unsigned short* __restrict__ Al,
    const unsigned short* __restrict__ Bh, const unsigned short* __restrict__ Bl,
    const float* __restrict__ bias, const float* __restrict__ bias2,
    float* __restrict__ Cf, unsigned short* __restrict__ Ch,
    unsigned short* __restrict__ Cl, int M, int N, int K) {
  __shared__ unsigned short Ash[64 * 32], Asl[64 * 32];
  __shared__ unsigned short Bsh[64 * 32], Bsl[64 * 32];
  const int tid = threadIdx.x;
  const int wave = tid >> 6, lane = tid & 63;
  const int quad = lane >> 4, l16 = lane & 15;
  const int bm = blockIdx.y * 64, bn = blockIdx.x * 64;
  const int lr = tid >> 2, lc = tid & 3;
  const int wofs = lr * 32 + ((lc ^ (lr & 3)) * 8);  // swizzled 16B chunk

  floatx4 acc[4] = {};
  // preload k-tile 0
  short8 avh = *(const short8*)(Ah + (size_t)(bm + lr) * K + lc * 8);
  short8 avl = *(const short8*)(Al + (size_t)(bm + lr) * K + lc * 8);
  short8 bvh = *(const short8*)(Bh + (size_t)(bn + lr) * K + lc * 8);
  short8 bvl = *(const short8*)(Bl + (size_t)(bn + lr) * K + lc * 8);

  for (int k0 = 0; k0 < K; k0 += 32) {
    lds_barrier();  // prior tile's LDS reads complete
    *(short8*)&Ash[wofs] = avh;
    *(short8*)&Asl[wofs] = avl;
    *(short8*)&Bsh[wofs] = bvh;
    *(short8*)&Bsl[wofs] = bvl;
    lds_barrier();
    if (k0 + 32 < K) {  // issue next tile's loads; MFMAs below hide latency
      avh = *(const short8*)(Ah + (size_t)(bm + lr) * K + k0 + 32 + lc * 8);
      avl = *(const short8*)(Al + (size_t)(bm + lr) * K + k0 + 32 + lc * 8);
      bvh = *(const short8*)(Bh + (size_t)(bn + lr) * K + k0 + 32 + lc * 8);
      bvl = *(const short8*)(Bl + (size_t)(bn + lr) * K + k0 + 32 + lc * 8);
    }
    const int bro = (wave * 16 + l16) * 32 + ((quad ^ (l16 & 3)) * 8);
    short8 bh = *(const short8*)&Bsh[bro];
    short8 bl = *(const short8*)&Bsl[bro];
#pragma unroll
    for (int i = 0; i < 4; ++i) {
      const int aro = (i * 16 + l16) * 32 + ((quad ^ (l16 & 3)) * 8);
      short8 ah = *(const short8*)&Ash[aro];
      short8 al = *(const short8*)&Asl[aro];
      acc[i] = __builtin_amdgcn_mfma_f32_16x16x32_bf16(al, bh, acc[i], 0, 0, 0);
      acc[i] = __builtin_amdgcn_mfma_f32_16x16x32_bf16(ah, bl, acc[i], 0, 0, 0);
      acc[i] = __builtin_amdgcn_mfma_f32_16x16x32_bf16(ah, bh, acc[i], 0, 0, 0);
    }
  }
  const int col = bn + wave * 16 + l16;
  float bj = bias[col];
  if (HAS_B2) bj += bias2[col];
#pragma unroll
  for (int i = 0; i < 4; ++i)
#pragma unroll
    for (int r = 0; r < 4; ++r) {
      int row = bm + i * 16 + quad * 4 + r;
      float v = acc[i][r] + bj;
      if (RELU) v = fmaxf(v, 0.f);
      if (OUT_SPLIT) {
        unsigned short hb = f2bf(v);
        Ch[(size_t)row * N + col] = hb;
        Cl[(size_t)row * N + col] = f2bf(v - bf2f(hb));
      } else {
        Cf[(size_t)row * N + col] = v;
      }
    }
}

// ---------------------------------------------------------------------------
// Pack W_hh [1024,256] fp32 -> bf16 B-fragment layout, wave-contiguous:
//   idx = ((kt*8 + w)*8 + i)*64 + lane, nt = (i>>1)*16 + w*2 + (i&1)
//   frag content: lane holds B[n = nt*16 + (lane&15)][kt*32 + (lane>>4)*8 + j]
// Per (kt, wave) the 8 fragments are contiguous 8 KB -> base + imm offsets.
// ---------------------------------------------------------------------------
__global__ __launch_bounds__(256) void pack_whh(const float* __restrict__ W,
                                                unsigned short* __restrict__ o) {
  int idx = blockIdx.x * 256 + threadIdx.x;  // ((kt*8+w)*8+i)*64 + lane
  int lane = idx & 63;
  int i = (idx >> 6) & 7;
  int w = (idx >> 9) & 7;
  int kt = idx >> 12;
  int nt = (i >> 1) * 16 + w * 2 + (i & 1);
  int n = nt * 16 + (lane & 15);
  int k0 = kt * 32 + (lane >> 4) * 8;
  const float* src = W + (size_t)n * 256 + k0;
  unsigned short* dst = o + (size_t)idx * 8;
#pragma unroll
  for (int j = 0; j < 8; ++j) dst[j] = f2bf(src[j]);
}

// ---------------------------------------------------------------------------
// Persistent LSTM: 256 blocks x 512 threads (8 waves), M=16 rows/block.
// W_hh kt-slices 6,7 live in LDS (128 KB, loaded once, conflict-free
// ds_read_b128 at MFMA-consume time); slices 0..5 stream from L2 via a
// rolling register pipeline:
//   consume: phase kt<6 reads bbuf[kt&3]; phase kt>=6 reads whh_lds.
//   issue:   kt=0..3 -> slice kt+2 into bbuf[(kt+2)&3];
//            kt=6,7  -> next step's slice kt-6 into bbuf[kt-6]
// -> <=3 buffers live, L2 stream continuous across the (lgkm-only) barrier.
// ---------------------------------------------------------------------------
__global__ __launch_bounds__(512, 2) void lstm_kernel(
    const float* __restrict__ xp,            // [4096,1024] fp32, gates i|f|g|o
    const unsigned short* __restrict__ whhf, // packed bf16 fragments
    float* __restrict__ out) {               // [4096,50,256] fp32
  __shared__ unsigned short h_frag[2][8][64][8];  // [buf][kt][lane][j] 16 KB
  __shared__ unsigned short whh_lds[65536];       // kt-slices 6,7: 128 KB

  const int tid = threadIdx.x;
  const int wave = tid >> 6;
  const int lane = tid & 63;
  const int quad = lane >> 4;
  const int l16 = lane & 15;
  const int block_m = blockIdx.x * 16;
  const int ut0 = wave * 2;

  for (int i = tid; i < 2 * 8 * 64 * 8; i += 512)
    ((unsigned short*)h_frag)[i] = 0;

  // LDS-cache W_hh slices 6,7 (whhf shorts [196608, 262144), 128 KB)
  {
    const short8* s = (const short8*)(whhf + 196608);
    short8* d = (short8*)whh_lds;
    for (int i = tid; i < 8192; i += 512) d[i] = s[i];
  }

  // x_part in registers, C-fragment layout; i = g*2 + utl
  floatx4 xpreg[8];
#pragma unroll
  for (int i = 0; i < 8; ++i) {
    int g = i >> 1, utl = i & 1;
    int col = g * 256 + (ut0 + utl) * 16 + l16;
    floatx4 v;
#pragma unroll
    for (int r = 0; r < 4; ++r)
      v[r] = xp[(size_t)(block_m + quad * 4 + r) * 1024 + col];
    xpreg[i] = v;
  }

  float c[2][4] = {};

  // Prologue of the rolling pipeline: slices 0,1 for t=0 phases 0,1.
  short8 bbuf[4][8];
#pragma unroll
  for (int sl = 0; sl < 2; ++sl) {
    const unsigned short* wb0 =
        whhf + ((size_t)((sl * 8 + wave) * 8) * 64 + lane) * 8;
#pragma unroll
    for (int i = 0; i < 8; ++i)
      bbuf[sl][i] = *(const short8*)(wb0 + i * 512);
  }

  __syncthreads();

  const size_t orow = (size_t)TSTEPS * HID;
  int cur = 0;

#pragma unroll 1
  for (int t = 0; t < TSTEPS; ++t) {
    // launder: keep streamed B loads + LDS B reads inside the loop
    const unsigned short* wb = whhf;
    asm volatile("" : "+s"(wb));
    unsigned lofs = 0;
    asm volatile("" : "+v"(lofs));

    floatx4 acc[8];

    // rolling A-fragment (h) prefetch, depth 1, within-step only
    short8 aab[2];
    aab[0] = *(const short8*)&h_frag[cur][0][lane][0];

#pragma unroll
    for (int kt = 0; kt < 8; ++kt) {
      // --- streamed-slice issue schedule ---
      if (kt < 4) {  // slice kt+2, consumed at phase kt+2 this step
        const int sl = kt + 2;
        const unsigned short* wbp =
            wb + ((size_t)((sl * 8 + wave) * 8) * 64 + lane) * 8;
#pragma unroll
        for (int i = 0; i < 8; ++i)
          bbuf[sl & 3][i] = *(const short8*)(wbp + i * 512);
      } else if (kt >= 6) {  // next step's slice kt-6 (t-invariant address)
        const int sl = kt - 6;
        const unsigned short* wbp =
            wb + ((size_t)((sl * 8 + wave) * 8) * 64 + lane) * 8;
#pragma unroll
        for (int i = 0; i < 8; ++i)
          bbuf[sl][i] = *(const short8*)(wbp + i * 512);
      }

      const short8 a = aab[kt & 1];
      if (kt < 7)  // next A-frag from LDS (cur buffer fully written)
        aab[(kt + 1) & 1] = *(const short8*)&h_frag[cur][kt + 1][lane][0];

      if (kt < 6) {  // B from the rolling register stream
#pragma unroll
        for (int i = 0; i < 8; ++i)
          acc[i] = __builtin_amdgcn_mfma_f32_16x16x32_bf16(
              a, bbuf[kt & 3][i], (kt == 0) ? xpreg[i] : acc[i], 0, 0, 0);
      } else {  // B from LDS (slices 6,7)
#pragma unroll
        for (int i = 0; i < 8; ++i) {
          const short8 bl = *(const short8*)&whh_lds[
              lofs + (size_t)((((kt - 6) * 8 + wave) * 8 + i) * 512) + lane * 8];
          acc[i] = __builtin_amdgcn_mfma_f32_16x16x32_bf16(a, bl, acc[i],
                                                           0, 0, 0);
        }
      }
    }

    const int nxt = cur ^ 1;
#pragma unroll
    for (int utl = 0; utl < 2; ++utl) {
      floatx4 gi = acc[0 + utl];
      floatx4 gf = acc[2 + utl];
      floatx4 gg = acc[4 + utl];
      floatx4 go = acc[6 + utl];
      const int u = (ut0 + utl) * 16 + l16;
      const int kt2 = u >> 5;
      const int lhi = ((u >> 3) & 3) << 4;
      const int j2 = u & 7;
#pragma unroll
      for (int r = 0; r < 4; ++r) {
        float iv = sigmf(gi[r]);
        float fv = sigmf(gf[r]);
        float gv = tanhf_(gg[r]);
        float ov = sigmf(go[r]);
        float cv = fmaf(fv, c[utl][r], iv * gv);
        c[utl][r] = cv;
        float hv = ov * tanhf_(cv);
        int mloc = quad * 4 + r;
        // non-temporal: don't let the 205 MB out-stream evict W_hh from L2
        __builtin_nontemporal_store(
            hv, &out[(size_t)(block_m + mloc) * orow + (size_t)t * HID + u]);
        h_frag[nxt][kt2][mloc | lhi][j2] = f2bf(hv);
      }
    }
    cur = nxt;
    lds_barrier();  // h_frag visibility only; vmcnt queue keeps flowing
  }
}

// ---------------------------------------------------------------------------
extern "C" void kernel_launch(void* const* d_in, const int* in_sizes, int n_in,
                              void* d_out, int out_size, void* d_ws, size_t ws_size,
                              hipStream_t stream) {
  const float* zs  = (const float*)d_in[0];
  const float* W1  = (const float*)d_in[1];
  const float* b1  = (const float*)d_in[2];
  const float* W2  = (const float*)d_in[3];
  const float* b2  = (const float*)d_in[4];
  const float* W3  = (const float*)d_in[5];
  const float* b3  = (const float*)d_in[6];
  const float* Wih = (const float*)d_in[7];
  const float* Whh = (const float*)d_in[8];
  const float* bih = (const float*)d_in[9];
  const float* bhh = (const float*)d_in[10];
  float* out = (float*)d_out;

  char* ws = (char*)d_ws;
  const size_t MB = 1024 * 1024;
  unsigned short* zs_h = (unsigned short*)(ws + 0 * MB);       // 2 MB
  unsigned short* zs_l = (unsigned short*)(ws + 2 * MB);       // 2 MB
  unsigned short* h1_h = (unsigned short*)(ws + 4 * MB);       // 4 MB
  unsigned short* h1_l = (unsigned short*)(ws + 8 * MB);       // 4 MB
  unsigned short* h2_h = (unsigned short*)(ws + 0 * MB);       // reuse zs (2 MB)
  unsigned short* h2_l = (unsigned short*)(ws + 2 * MB);       // reuse zs (2 MB)
  unsigned short* zb_h = (unsigned short*)(ws + 12 * MB);      // 1 MB
  unsigned short* zb_l = (unsigned short*)(ws + 13 * MB);      // 1 MB
  unsigned short* w1_h = (unsigned short*)(ws + 14 * MB);                 // 256 KB
  unsigned short* w1_l = (unsigned short*)(ws + 14 * MB + 256 * 1024);
  unsigned short* w2_h = (unsigned short*)(ws + 14 * MB + 512 * 1024);
  unsigned short* w2_l = (unsigned short*)(ws + 14 * MB + 768 * 1024);
  unsigned short* w3_h = (unsigned short*)(ws + 15 * MB);                 // 64 KB
  unsigned short* w3_l = (unsigned short*)(ws + 15 * MB + 64 * 1024);
  unsigned short* wi_h = (unsigned short*)(ws + 15 * MB + 128 * 1024);    // 256 KB
  unsigned short* wi_l = (unsigned short*)(ws + 15 * MB + 384 * 1024);
  float* xp            = (float*)(ws + 16 * MB);               // 16 MB
  unsigned short* whhf = (unsigned short*)(ws + 32 * MB);      // 512 KB

  // fp32 -> hi/lo bf16 splits, one fused launch (zs, W1, W2, W3, Wih)
  split_all<<<1440, 256, 0, stream>>>(zs, zs_h, zs_l, W1, w1_h, w1_l,
                                      W2, w2_h, w2_l, W3, w3_h, w3_l,
                                      Wih, wi_h, wi_l);

  // MLP: h1 = relu(zs@W1^T+b1); h2 = relu(h1@W2^T+b2); zb = h2@W3^T+b3
  gemm_df<1, 1, 0><<<dim3(512 / 64, BATCH / 64), 256, 0, stream>>>(
      zs_h, zs_l, w1_h, w1_l, b1, nullptr, nullptr, h1_h, h1_l, BATCH, 512, 256);
  gemm_df<1, 1, 0><<<dim3(256 / 64, BATCH / 64), 256, 0, stream>>>(
      h1_h, h1_l, w2_h, w2_l, b2, nullptr, nullptr, h2_h, h2_l, BATCH, 256, 512);
  gemm_df<0, 1, 0><<<dim3(128 / 64, BATCH / 64), 256, 0, stream>>>(
      h2_h, h2_l, w3_h, w3_l, b3, nullptr, nullptr, zb_h, zb_l, BATCH, 128, 256);
  // xp = zb@Wih^T + b_ih + b_hh  (fp32 out)
  gemm_df<0, 0, 1><<<dim3(1024 / 64, BATCH / 64), 256, 0, stream>>>(
      zb_h, zb_l, wi_h, wi_l, bih, bhh, xp, nullptr, nullptr, BATCH, 1024, 128);

  pack_whh<<<128, 256, 0, stream>>>(Whh, whhf);

  lstm_kernel<<<BATCH / 16, 512, 0, stream>>>(xp, whhf, out);
}

// Round 4
// 391.885 us; speedup vs baseline: 1.7180x; 1.1498x over previous
//
#include <hip/hip_runtime.h>
#include <stdint.h>

// ---------------------------------------------------------------------------
// Predictor: MLP (256->512->256->128) -> LSTM(128 in, 256 hidden, T=50)
//   - MLP via split-bf16 (hi+lo) MFMA gemms, lgkm-only barriers + tile
//     prefetch so global latency overlaps MFMA.
//   - LSTM v4: 256 blocks x 512 thr, M=16 rows/block, 50 steps in-kernel.
//     Kernel is L2-BW-bound on the W_hh stream. Three-tier W_hh residency:
//       slices 3,4,5 -> PERSISTENT REGISTERS (96 VGPR/wave, loaded once;
//                       t-invariant, LICM-hoisted on purpose)
//       slices 6,7   -> LDS (128 KB, loaded once, ds_read_b128 at consume)
//       slices 0,1,2 -> streamed from L2 via 2 rolling reg buffers
//                       (refill A<-2 @kt0, A<-0' @kt5, B<-1' @kt6; issues
//                       cross the lgkm-only step barrier so L2 never idles)
//     L2 stream: 512 (v2) -> 384 (v3) -> 192 KB/CU/step. acc-init fused
//     into kt=0 MFMA (C=xpreg); non-temporal output stores.
// ---------------------------------------------------------------------------

typedef short short8 __attribute__((ext_vector_type(8)));
typedef float floatx4 __attribute__((ext_vector_type(4)));
typedef unsigned short ushort4v __attribute__((ext_vector_type(4)));

#define BATCH 4096
#define HID 256
#define TSTEPS 50

static __device__ __forceinline__ unsigned short f2bf(float x) {
  union { float f; unsigned int u; } v; v.f = x;
  unsigned int r = (v.u + 0x7fffu + ((v.u >> 16) & 1u)) >> 16;  // RNE
  return (unsigned short)r;
}
static __device__ __forceinline__ float bf2f(unsigned short h) {
  union { unsigned int u; float f; } v; v.u = ((unsigned int)h) << 16;
  return v.f;
}
static __device__ __forceinline__ float sigmf(float x) {
  return __builtin_amdgcn_rcpf(1.0f + __expf(-x));
}
static __device__ __forceinline__ float tanhf_(float x) {
  return 1.0f - 2.0f * __builtin_amdgcn_rcpf(__expf(2.0f * x) + 1.0f);
}

// lgkm-only barrier: LDS visibility without draining the vmcnt queue.
static __device__ __forceinline__ void lds_barrier() {
  __asm__ volatile("s_waitcnt lgkmcnt(0)\n\ts_barrier" ::: "memory");
}

// ---------------------------------------------------------------------------
// Fused fp32 -> (hi,lo) bf16 split for all 5 arrays in one launch.
// Work item = one float4. Segment boundaries (in float4 units) hard-coded.
// ---------------------------------------------------------------------------
__global__ __launch_bounds__(256) void split_all(
    const float* __restrict__ s0, unsigned short* __restrict__ h0, unsigned short* __restrict__ l0,
    const float* __restrict__ s1, unsigned short* __restrict__ h1, unsigned short* __restrict__ l1,
    const float* __restrict__ s2, unsigned short* __restrict__ h2, unsigned short* __restrict__ l2,
    const float* __restrict__ s3, unsigned short* __restrict__ h3, unsigned short* __restrict__ l3,
    const float* __restrict__ s4, unsigned short* __restrict__ h4, unsigned short* __restrict__ l4) {
  int i = blockIdx.x * 256 + threadIdx.x;
  const float* src; unsigned short *dh, *dl; int off;
  if (i < 262144)      { src = s0; dh = h0; dl = l0; off = i; }
  else if (i < 294912) { src = s1; dh = h1; dl = l1; off = i - 262144; }
  else if (i < 327680) { src = s2; dh = h2; dl = l2; off = i - 294912; }
  else if (i < 335872) { src = s3; dh = h3; dl = l3; off = i - 327680; }
  else if (i < 368640) { src = s4; dh = h4; dl = l4; off = i - 335872; }
  else return;
  float4 v = ((const float4*)src)[off];
  float cc[4] = {v.x, v.y, v.z, v.w};
  ushort4v h, l;
#pragma unroll
  for (int j = 0; j < 4; ++j) {
    unsigned short hb = f2bf(cc[j]);
    h[j] = hb;
    l[j] = f2bf(cc[j] - bf2f(hb));
  }
  ((ushort4v*)dh)[off] = h;
  ((ushort4v*)dl)[off] = l;
}

// ---------------------------------------------------------------------------
// Split-bf16 MFMA GEMM: C = act(A @ B^T + bias (+bias2)), A:[M,K], B:[N,K]
// hi/lo bf16 pairs, row-major. 64x64 tile, 256 thr, BK=32, XOR-swizzled LDS.
// Pipelined: next k-tile's global loads issue before this tile's MFMAs;
// lgkm-only barriers keep the vmcnt queue flowing.
// ---------------------------------------------------------------------------
template <int RELU, int OUT_SPLIT, int HAS_B2>
__global__ __launch_bounds__(256) void gemm_df(
    const unsigned short* __restrict__ Ah, const unsigned short* __restrict__ Al,
    const unsigned short* __restrict__ Bh, const unsigned short* __restrict__ Bl,
    const float* __restrict__ bias, const float* __restrict__ bias2,
    float* __restrict__ Cf, unsigned short* __restrict__ Ch,
    unsigned short* __restrict__ Cl, int M, int N, int K) {
  __shared__ unsigned short Ash[64 * 32], Asl[64 * 32];
  __shared__ unsigned short Bsh[64 * 32], Bsl[64 * 32];
  const int tid = threadIdx.x;
  const int wave = tid >> 6, lane = tid & 63;
  const int quad = lane >> 4, l16 = lane & 15;
  const int bm = blockIdx.y * 64, bn = blockIdx.x * 64;
  const int lr = tid >> 2, lc = tid & 3;
  const int wofs = lr * 32 + ((lc ^ (lr & 3)) * 8);  // swizzled 16B chunk

  floatx4 acc[4] = {};
  // preload k-tile 0
  short8 avh = *(const short8*)(Ah + (size_t)(bm + lr) * K + lc * 8);
  short8 avl = *(const short8*)(Al + (size_t)(bm + lr) * K + lc * 8);
  short8 bvh = *(const short8*)(Bh + (size_t)(bn + lr) * K + lc * 8);
  short8 bvl = *(const short8*)(Bl + (size_t)(bn + lr) * K + lc * 8);

  for (int k0 = 0; k0 < K; k0 += 32) {
    lds_barrier();  // prior tile's LDS reads complete
    *(short8*)&Ash[wofs] = avh;
    *(short8*)&Asl[wofs] = avl;
    *(short8*)&Bsh[wofs] = bvh;
    *(short8*)&Bsl[wofs] = bvl;
    lds_barrier();
    if (k0 + 32 < K) {  // issue next tile's loads; MFMAs below hide latency
      avh = *(const short8*)(Ah + (size_t)(bm + lr) * K + k0 + 32 + lc * 8);
      avl = *(const short8*)(Al + (size_t)(bm + lr) * K + k0 + 32 + lc * 8);
      bvh = *(const short8*)(Bh + (size_t)(bn + lr) * K + k0 + 32 + lc * 8);
      bvl = *(const short8*)(Bl + (size_t)(bn + lr) * K + k0 + 32 + lc * 8);
    }
    const int bro = (wave * 16 + l16) * 32 + ((quad ^ (l16 & 3)) * 8);
    short8 bh = *(const short8*)&Bsh[bro];
    short8 bl = *(const short8*)&Bsl[bro];
#pragma unroll
    for (int i = 0; i < 4; ++i) {
      const int aro = (i * 16 + l16) * 32 + ((quad ^ (l16 & 3)) * 8);
      short8 ah = *(const short8*)&Ash[aro];
      short8 al = *(const short8*)&Asl[aro];
      acc[i] = __builtin_amdgcn_mfma_f32_16x16x32_bf16(al, bh, acc[i], 0, 0, 0);
      acc[i] = __builtin_amdgcn_mfma_f32_16x16x32_bf16(ah, bl, acc[i], 0, 0, 0);
      acc[i] = __builtin_amdgcn_mfma_f32_16x16x32_bf16(ah, bh, acc[i], 0, 0, 0);
    }
  }
  const int col = bn + wave * 16 + l16;
  float bj = bias[col];
  if (HAS_B2) bj += bias2[col];
#pragma unroll
  for (int i = 0; i < 4; ++i)
#pragma unroll
    for (int r = 0; r < 4; ++r) {
      int row = bm + i * 16 + quad * 4 + r;
      float v = acc[i][r] + bj;
      if (RELU) v = fmaxf(v, 0.f);
      if (OUT_SPLIT) {
        unsigned short hb = f2bf(v);
        Ch[(size_t)row * N + col] = hb;
        Cl[(size_t)row * N + col] = f2bf(v - bf2f(hb));
      } else {
        Cf[(size_t)row * N + col] = v;
      }
    }
}

// ---------------------------------------------------------------------------
// Pack W_hh [1024,256] fp32 -> bf16 B-fragment layout, wave-contiguous:
//   idx = ((kt*8 + w)*8 + i)*64 + lane, nt = (i>>1)*16 + w*2 + (i&1)
//   frag content: lane holds B[n = nt*16 + (lane&15)][kt*32 + (lane>>4)*8 + j]
// Per (kt, wave) the 8 fragments are contiguous 8 KB -> base + imm offsets.
// ---------------------------------------------------------------------------
__global__ __launch_bounds__(256) void pack_whh(const float* __restrict__ W,
                                                unsigned short* __restrict__ o) {
  int idx = blockIdx.x * 256 + threadIdx.x;  // ((kt*8+w)*8+i)*64 + lane
  int lane = idx & 63;
  int i = (idx >> 6) & 7;
  int w = (idx >> 9) & 7;
  int kt = idx >> 12;
  int nt = (i >> 1) * 16 + w * 2 + (i & 1);
  int n = nt * 16 + (lane & 15);
  int k0 = kt * 32 + (lane >> 4) * 8;
  const float* src = W + (size_t)n * 256 + k0;
  unsigned short* dst = o + (size_t)idx * 8;
#pragma unroll
  for (int j = 0; j < 8; ++j) dst[j] = f2bf(src[j]);
}

// ---------------------------------------------------------------------------
// Persistent LSTM: 256 blocks x 512 threads (8 waves), M=16 rows/block.
// W_hh residency: slices 3,4,5 in persistent regs; 6,7 in LDS; 0,1,2
// streamed via 2 rolling buffers (bA,bB):
//   consume: kt0=A(0) kt1=B(1) kt2=A(2) kt3..5=pers[0..2] kt6,7=LDS
//   refill:  kt0: A<-slice2 (after consume; 2-phase lead)
//            kt5: A<-slice0' (next step)   kt6: B<-slice1' (next step)
// Cross-barrier issues keep the L2 pipe busy through the lgkm-only barrier.
// ---------------------------------------------------------------------------
__global__ __launch_bounds__(512, 2) void lstm_kernel(
    const float* __restrict__ xp,            // [4096,1024] fp32, gates i|f|g|o
    const unsigned short* __restrict__ whhf, // packed bf16 fragments
    float* __restrict__ out) {               // [4096,50,256] fp32
  __shared__ unsigned short h_frag[2][8][64][8];  // [buf][kt][lane][j] 16 KB
  __shared__ unsigned short whh_lds[65536];       // kt-slices 6,7: 128 KB

  const int tid = threadIdx.x;
  const int wave = tid >> 6;
  const int lane = tid & 63;
  const int quad = lane >> 4;
  const int l16 = lane & 15;
  const int block_m = blockIdx.x * 16;
  const int ut0 = wave * 2;

  for (int i = tid; i < 2 * 8 * 64 * 8; i += 512)
    ((unsigned short*)h_frag)[i] = 0;

  // LDS-cache W_hh slices 6,7 (whhf shorts [196608, 262144), 128 KB)
  {
    const short8* s = (const short8*)(whhf + 196608);
    short8* d = (short8*)whh_lds;
    for (int i = tid; i < 8192; i += 512) d[i] = s[i];
  }

  // x_part in registers, C-fragment layout; i = g*2 + utl
  floatx4 xpreg[8];
#pragma unroll
  for (int i = 0; i < 8; ++i) {
    int g = i >> 1, utl = i & 1;
    int col = g * 256 + (ut0 + utl) * 16 + l16;
    floatx4 v;
#pragma unroll
    for (int r = 0; r < 4; ++r)
      v[r] = xp[(size_t)(block_m + quad * 4 + r) * 1024 + col];
    xpreg[i] = v;
  }

  float c[2][4] = {};

  // PERSISTENT register slices 3,4,5 (t-invariant; intentionally hoisted).
  short8 pers[3][8];
#pragma unroll
  for (int sl = 0; sl < 3; ++sl) {
    const unsigned short* wb0 =
        whhf + ((size_t)(((sl + 3) * 8 + wave) * 8) * 64 + lane) * 8;
#pragma unroll
    for (int i = 0; i < 8; ++i)
      pers[sl][i] = *(const short8*)(wb0 + i * 512);
  }

  // Stream prologue: slices 0,1 for t=0 into the two rolling buffers.
  short8 bA[8], bB[8];
  {
    const unsigned short* w0 =
        whhf + ((size_t)((0 * 8 + wave) * 8) * 64 + lane) * 8;
    const unsigned short* w1 =
        whhf + ((size_t)((1 * 8 + wave) * 8) * 64 + lane) * 8;
#pragma unroll
    for (int i = 0; i < 8; ++i) {
      bA[i] = *(const short8*)(w0 + i * 512);
      bB[i] = *(const short8*)(w1 + i * 512);
    }
  }

  __syncthreads();

  const size_t orow = (size_t)TSTEPS * HID;
  int cur = 0;

#pragma unroll 1
  for (int t = 0; t < TSTEPS; ++t) {
    // launder: keep streamed B loads + LDS B reads inside the loop
    const unsigned short* wb = whhf;
    asm volatile("" : "+s"(wb));
    unsigned lofs = 0;
    asm volatile("" : "+v"(lofs));

    floatx4 acc[8];

    // rolling A-fragment (h) prefetch, depth 1, within-step only
    short8 aab[2];
    aab[0] = *(const short8*)&h_frag[cur][0][lane][0];

#pragma unroll
    for (int kt = 0; kt < 8; ++kt) {
      const short8 a = aab[kt & 1];
      if (kt < 7)  // next A-frag from LDS (cur buffer fully written)
        aab[(kt + 1) & 1] = *(const short8*)&h_frag[cur][kt + 1][lane][0];

      if (kt == 0) {
#pragma unroll
        for (int i = 0; i < 8; ++i)
          acc[i] = __builtin_amdgcn_mfma_f32_16x16x32_bf16(a, bA[i],
                                                           xpreg[i], 0, 0, 0);
        // refill A <- slice 2 (consumed at kt=2; WAR on bA resolved by
        // MFMA operand reads above)
        const unsigned short* wbp =
            wb + ((size_t)((2 * 8 + wave) * 8) * 64 + lane) * 8;
#pragma unroll
        for (int i = 0; i < 8; ++i) bA[i] = *(const short8*)(wbp + i * 512);
      } else if (kt == 1) {
#pragma unroll
        for (int i = 0; i < 8; ++i)
          acc[i] = __builtin_amdgcn_mfma_f32_16x16x32_bf16(a, bB[i],
                                                           acc[i], 0, 0, 0);
      } else if (kt == 2) {
#pragma unroll
        for (int i = 0; i < 8; ++i)
          acc[i] = __builtin_amdgcn_mfma_f32_16x16x32_bf16(a, bA[i],
                                                           acc[i], 0, 0, 0);
      } else if (kt <= 5) {
#pragma unroll
        for (int i = 0; i < 8; ++i)
          acc[i] = __builtin_amdgcn_mfma_f32_16x16x32_bf16(a, pers[kt - 3][i],
                                                           acc[i], 0, 0, 0);
        if (kt == 5) {  // refill A <- next step's slice 0
          const unsigned short* wbp =
              wb + ((size_t)((0 * 8 + wave) * 8) * 64 + lane) * 8;
#pragma unroll
          for (int i = 0; i < 8; ++i) bA[i] = *(const short8*)(wbp + i * 512);
        }
      } else {  // kt = 6,7: B from LDS (slices 6,7)
#pragma unroll
        for (int i = 0; i < 8; ++i) {
          const short8 bl = *(const short8*)&whh_lds[
              lofs + (size_t)((((kt - 6) * 8 + wave) * 8 + i) * 512) + lane * 8];
          acc[i] = __builtin_amdgcn_mfma_f32_16x16x32_bf16(a, bl, acc[i],
                                                           0, 0, 0);
        }
        if (kt == 6) {  // refill B <- next step's slice 1
          const unsigned short* wbp =
              wb + ((size_t)((1 * 8 + wave) * 8) * 64 + lane) * 8;
#pragma unroll
          for (int i = 0; i < 8; ++i) bB[i] = *(const short8*)(wbp + i * 512);
        }
      }
    }

    const int nxt = cur ^ 1;
#pragma unroll
    for (int utl = 0; utl < 2; ++utl) {
      floatx4 gi = acc[0 + utl];
      floatx4 gf = acc[2 + utl];
      floatx4 gg = acc[4 + utl];
      floatx4 go = acc[6 + utl];
      const int u = (ut0 + utl) * 16 + l16;
      const int kt2 = u >> 5;
      const int lhi = ((u >> 3) & 3) << 4;
      const int j2 = u & 7;
#pragma unroll
      for (int r = 0; r < 4; ++r) {
        float iv = sigmf(gi[r]);
        float fv = sigmf(gf[r]);
        float gv = tanhf_(gg[r]);
        float ov = sigmf(go[r]);
        float cv = fmaf(fv, c[utl][r], iv * gv);
        c[utl][r] = cv;
        float hv = ov * tanhf_(cv);
        int mloc = quad * 4 + r;
        // non-temporal: don't let the 205 MB out-stream evict W_hh from L2
        __builtin_nontemporal_store(
            hv, &out[(size_t)(block_m + mloc) * orow + (size_t)t * HID + u]);
        h_frag[nxt][kt2][mloc | lhi][j2] = f2bf(hv);
      }
    }
    cur = nxt;
    lds_barrier();  // h_frag visibility only; vmcnt queue keeps flowing
  }
}

// ---------------------------------------------------------------------------
extern "C" void kernel_launch(void* const* d_in, const int* in_sizes, int n_in,
                              void* d_out, int out_size, void* d_ws, size_t ws_size,
                              hipStream_t stream) {
  const float* zs  = (const float*)d_in[0];
  const float* W1  = (const float*)d_in[1];
  const float* b1  = (const float*)d_in[2];
  const float* W2  = (const float*)d_in[3];
  const float* b2  = (const float*)d_in[4];
  const float* W3  = (const float*)d_in[5];
  const float* b3  = (const float*)d_in[6];
  const float* Wih = (const float*)d_in[7];
  const float* Whh = (const float*)d_in[8];
  const float* bih = (const float*)d_in[9];
  const float* bhh = (const float*)d_in[10];
  float* out = (float*)d_out;

  char* ws = (char*)d_ws;
  const size_t MB = 1024 * 1024;
  unsigned short* zs_h = (unsigned short*)(ws + 0 * MB);       // 2 MB
  unsigned short* zs_l = (unsigned short*)(ws + 2 * MB);       // 2 MB
  unsigned short* h1_h = (unsigned short*)(ws + 4 * MB);       // 4 MB
  unsigned short* h1_l = (unsigned short*)(ws + 8 * MB);       // 4 MB
  unsigned short* h2_h = (unsigned short*)(ws + 0 * MB);       // reuse zs (2 MB)
  unsigned short* h2_l = (unsigned short*)(ws + 2 * MB);       // reuse zs (2 MB)
  unsigned short* zb_h = (unsigned short*)(ws + 12 * MB);      // 1 MB
  unsigned short* zb_l = (unsigned short*)(ws + 13 * MB);      // 1 MB
  unsigned short* w1_h = (unsigned short*)(ws + 14 * MB);                 // 256 KB
  unsigned short* w1_l = (unsigned short*)(ws + 14 * MB + 256 * 1024);
  unsigned short* w2_h = (unsigned short*)(ws + 14 * MB + 512 * 1024);
  unsigned short* w2_l = (unsigned short*)(ws + 14 * MB + 768 * 1024);
  unsigned short* w3_h = (unsigned short*)(ws + 15 * MB);                 // 64 KB
  unsigned short* w3_l = (unsigned short*)(ws + 15 * MB + 64 * 1024);
  unsigned short* wi_h = (unsigned short*)(ws + 15 * MB + 128 * 1024);    // 256 KB
  unsigned short* wi_l = (unsigned short*)(ws + 15 * MB + 384 * 1024);
  float* xp            = (float*)(ws + 16 * MB);               // 16 MB
  unsigned short* whhf = (unsigned short*)(ws + 32 * MB);      // 512 KB

  // fp32 -> hi/lo bf16 splits, one fused launch (zs, W1, W2, W3, Wih)
  split_all<<<1440, 256, 0, stream>>>(zs, zs_h, zs_l, W1, w1_h, w1_l,
                                      W2, w2_h, w2_l, W3, w3_h, w3_l,
                                      Wih, wi_h, wi_l);

  // MLP: h1 = relu(zs@W1^T+b1); h2 = relu(h1@W2^T+b2); zb = h2@W3^T+b3
  gemm_df<1, 1, 0><<<dim3(512 / 64, BATCH / 64), 256, 0, stream>>>(
      zs_h, zs_l, w1_h, w1_l, b1, nullptr, nullptr, h1_h, h1_l, BATCH, 512, 256);
  gemm_df<1, 1, 0><<<dim3(256 / 64, BATCH / 64), 256, 0, stream>>>(
      h1_h, h1_l, w2_h, w2_l, b2, nullptr, nullptr, h2_h, h2_l, BATCH, 256, 512);
  gemm_df<0, 1, 0><<<dim3(128 / 64, BATCH / 64), 256, 0, stream>>>(
      h2_h, h2_l, w3_h, w3_l, b3, nullptr, nullptr, zb_h, zb_l, BATCH, 128, 256);
  // xp = zb@Wih^T + b_ih + b_hh  (fp32 out)
  gemm_df<0, 0, 1><<<dim3(1024 / 64, BATCH / 64), 256, 0, stream>>>(
      zb_h, zb_l, wi_h, wi_l, bih, bhh, xp, nullptr, nullptr, BATCH, 1024, 128);

  pack_whh<<<128, 256, 0, stream>>>(Whh, whhf);

  lstm_kernel<<<BATCH / 16, 512, 0, stream>>>(xp, whhf, out);
}

// Round 5
// 382.991 us; speedup vs baseline: 1.7579x; 1.0232x over previous
//
#include <hip/hip_runtime.h>
#include <stdint.h>

// ---------------------------------------------------------------------------
// Predictor: MLP (256->512->256->128) -> LSTM(128 in, 256 hidden, T=50)
//   - MLP via split-bf16 (hi+lo) MFMA gemms, lgkm-only barriers + tile
//     prefetch so global latency overlaps MFMA.
//   - LSTM v5: 256 blocks x 512 thr, M=16 rows/block, 50 steps in-kernel.
//     L2-BW-bound on the W_hh stream (marginal rate ~68 B/cyc/CU, verified
//     across v2->v3->v4). W_hh residency this rev:
//       slices 1,2,3,5 -> PERSISTENT REGISTERS (128 VGPR/wave, loaded once)
//       slices 6,7     -> LDS (128 KB, loaded once, ds_read_b128 at consume)
//       slices 0,4     -> streamed from L2 through a SINGLE rolling buffer
//                         (consume 0 @kt0 -> refill<-4; consume 4 @kt4 ->
//                          refill<-0'; 4-phase issue-to-use lead both ways,
//                          crossing the lgkm-only step barrier)
//     L2 stream: 512 (v2) -> 384 (v3) -> 192 (v4) -> 128 KB/CU/step.
//     Net register delta vs v4 = 0 (one more pers slice, one fewer buffer).
//     acc-init fused into kt=0 MFMA (C=xpreg); non-temporal output stores.
//   - pack_whh folded into split_all (one fewer launch).
// ---------------------------------------------------------------------------

typedef short short8 __attribute__((ext_vector_type(8)));
typedef float floatx4 __attribute__((ext_vector_type(4)));
typedef unsigned short ushort4v __attribute__((ext_vector_type(4)));

#define BATCH 4096
#define HID 256
#define TSTEPS 50

static __device__ __forceinline__ unsigned short f2bf(float x) {
  union { float f; unsigned int u; } v; v.f = x;
  unsigned int r = (v.u + 0x7fffu + ((v.u >> 16) & 1u)) >> 16;  // RNE
  return (unsigned short)r;
}
static __device__ __forceinline__ float bf2f(unsigned short h) {
  union { unsigned int u; float f; } v; v.u = ((unsigned int)h) << 16;
  return v.f;
}
static __device__ __forceinline__ float sigmf(float x) {
  return __builtin_amdgcn_rcpf(1.0f + __expf(-x));
}
static __device__ __forceinline__ float tanhf_(float x) {
  return 1.0f - 2.0f * __builtin_amdgcn_rcpf(__expf(2.0f * x) + 1.0f);
}

// lgkm-only barrier: LDS visibility without draining the vmcnt queue.
static __device__ __forceinline__ void lds_barrier() {
  __asm__ volatile("s_waitcnt lgkmcnt(0)\n\ts_barrier" ::: "memory");
}

// ---------------------------------------------------------------------------
// Fused preprocessing, one launch:
//   blocks [0,1440):    fp32 -> (hi,lo) bf16 split (zs, W1, W2, W3, Wih)
//   blocks [1440,1568): pack W_hh [1024,256] fp32 -> bf16 B-fragment layout,
//     idx = ((kt*8 + w)*8 + i)*64 + lane, nt = (i>>1)*16 + w*2 + (i&1);
//     lane holds B[n = nt*16 + (lane&15)][kt*32 + (lane>>4)*8 + j].
//     Per (kt, wave) the 8 fragments are contiguous 8 KB.
// ---------------------------------------------------------------------------
__global__ __launch_bounds__(256) void split_all(
    const float* __restrict__ s0, unsigned short* __restrict__ h0, unsigned short* __restrict__ l0,
    const float* __restrict__ s1, unsigned short* __restrict__ h1, unsigned short* __restrict__ l1,
    const float* __restrict__ s2, unsigned short* __restrict__ h2, unsigned short* __restrict__ l2,
    const float* __restrict__ s3, unsigned short* __restrict__ h3, unsigned short* __restrict__ l3,
    const float* __restrict__ s4, unsigned short* __restrict__ h4, unsigned short* __restrict__ l4,
    const float* __restrict__ Wh, unsigned short* __restrict__ whhf) {
  if (blockIdx.x >= 1440) {  // pack_whh tail: 128 blocks
    int idx = (blockIdx.x - 1440) * 256 + threadIdx.x;  // ((kt*8+w)*8+i)*64+lane
    int lane = idx & 63;
    int i = (idx >> 6) & 7;
    int w = (idx >> 9) & 7;
    int kt = idx >> 12;
    int nt = (i >> 1) * 16 + w * 2 + (i & 1);
    int n = nt * 16 + (lane & 15);
    int k0 = kt * 32 + (lane >> 4) * 8;
    const float* src = Wh + (size_t)n * 256 + k0;
    unsigned short* dst = whhf + (size_t)idx * 8;
#pragma unroll
    for (int j = 0; j < 8; ++j) dst[j] = f2bf(src[j]);
    return;
  }
  int i = blockIdx.x * 256 + threadIdx.x;
  const float* src; unsigned short *dh, *dl; int off;
  if (i < 262144)      { src = s0; dh = h0; dl = l0; off = i; }
  else if (i < 294912) { src = s1; dh = h1; dl = l1; off = i - 262144; }
  else if (i < 327680) { src = s2; dh = h2; dl = l2; off = i - 294912; }
  else if (i < 335872) { src = s3; dh = h3; dl = l3; off = i - 327680; }
  else if (i < 368640) { src = s4; dh = h4; dl = l4; off = i - 335872; }
  else return;
  float4 v = ((const float4*)src)[off];
  float cc[4] = {v.x, v.y, v.z, v.w};
  ushort4v h, l;
#pragma unroll
  for (int j = 0; j < 4; ++j) {
    unsigned short hb = f2bf(cc[j]);
    h[j] = hb;
    l[j] = f2bf(cc[j] - bf2f(hb));
  }
  ((ushort4v*)dh)[off] = h;
  ((ushort4v*)dl)[off] = l;
}

// ---------------------------------------------------------------------------
// Split-bf16 MFMA GEMM: C = act(A @ B^T + bias (+bias2)), A:[M,K], B:[N,K]
// hi/lo bf16 pairs, row-major. 64x64 tile, 256 thr, BK=32, XOR-swizzled LDS.
// Pipelined: next k-tile's global loads issue before this tile's MFMAs;
// lgkm-only barriers keep the vmcnt queue flowing.
// ---------------------------------------------------------------------------
template <int RELU, int OUT_SPLIT, int HAS_B2>
__global__ __launch_bounds__(256) void gemm_df(
    const unsigned short* __restrict__ Ah, const unsigned short* __restrict__ Al,
    const unsigned short* __restrict__ Bh, const unsigned short* __restrict__ Bl,
    const float* __restrict__ bias, const float* __restrict__ bias2,
    float* __restrict__ Cf, unsigned short* __restrict__ Ch,
    unsigned short* __restrict__ Cl, int M, int N, int K) {
  __shared__ unsigned short Ash[64 * 32], Asl[64 * 32];
  __shared__ unsigned short Bsh[64 * 32], Bsl[64 * 32];
  const int tid = threadIdx.x;
  const int wave = tid >> 6, lane = tid & 63;
  const int quad = lane >> 4, l16 = lane & 15;
  const int bm = blockIdx.y * 64, bn = blockIdx.x * 64;
  const int lr = tid >> 2, lc = tid & 3;
  const int wofs = lr * 32 + ((lc ^ (lr & 3)) * 8);  // swizzled 16B chunk

  floatx4 acc[4] = {};
  // preload k-tile 0
  short8 avh = *(const short8*)(Ah + (size_t)(bm + lr) * K + lc * 8);
  short8 avl = *(const short8*)(Al + (size_t)(bm + lr) * K + lc * 8);
  short8 bvh = *(const short8*)(Bh + (size_t)(bn + lr) * K + lc * 8);
  short8 bvl = *(const short8*)(Bl + (size_t)(bn + lr) * K + lc * 8);

  for (int k0 = 0; k0 < K; k0 += 32) {
    lds_barrier();  // prior tile's LDS reads complete
    *(short8*)&Ash[wofs] = avh;
    *(short8*)&Asl[wofs] = avl;
    *(short8*)&Bsh[wofs] = bvh;
    *(short8*)&Bsl[wofs] = bvl;
    lds_barrier();
    if (k0 + 32 < K) {  // issue next tile's loads; MFMAs below hide latency
      avh = *(const short8*)(Ah + (size_t)(bm + lr) * K + k0 + 32 + lc * 8);
      avl = *(const short8*)(Al + (size_t)(bm + lr) * K + k0 + 32 + lc * 8);
      bvh = *(const short8*)(Bh + (size_t)(bn + lr) * K + k0 + 32 + lc * 8);
      bvl = *(const short8*)(Bl + (size_t)(bn + lr) * K + k0 + 32 + lc * 8);
    }
    const int bro = (wave * 16 + l16) * 32 + ((quad ^ (l16 & 3)) * 8);
    short8 bh = *(const short8*)&Bsh[bro];
    short8 bl = *(const short8*)&Bsl[bro];
#pragma unroll
    for (int i = 0; i < 4; ++i) {
      const int aro = (i * 16 + l16) * 32 + ((quad ^ (l16 & 3)) * 8);
      short8 ah = *(const short8*)&Ash[aro];
      short8 al = *(const short8*)&Asl[aro];
      acc[i] = __builtin_amdgcn_mfma_f32_16x16x32_bf16(al, bh, acc[i], 0, 0, 0);
      acc[i] = __builtin_amdgcn_mfma_f32_16x16x32_bf16(ah, bl, acc[i], 0, 0, 0);
      acc[i] = __builtin_amdgcn_mfma_f32_16x16x32_bf16(ah, bh, acc[i], 0, 0, 0);
    }
  }
  const int col = bn + wave * 16 + l16;
  float bj = bias[col];
  if (HAS_B2) bj += bias2[col];
#pragma unroll
  for (int i = 0; i < 4; ++i)
#pragma unroll
    for (int r = 0; r < 4; ++r) {
      int row = bm + i * 16 + quad * 4 + r;
      float v = acc[i][r] + bj;
      if (RELU) v = fmaxf(v, 0.f);
      if (OUT_SPLIT) {
        unsigned short hb = f2bf(v);
        Ch[(size_t)row * N + col] = hb;
        Cl[(size_t)row * N + col] = f2bf(v - bf2f(hb));
      } else {
        Cf[(size_t)row * N + col] = v;
      }
    }
}

// ---------------------------------------------------------------------------
// Persistent LSTM: 256 blocks x 512 threads (8 waves), M=16 rows/block.
// W_hh residency: slices 1,2,3,5 persistent regs; 6,7 LDS; 0,4 streamed
// through ONE rolling buffer bA:
//   consume: kt0=bA(0) kt1..3=pers[0..2] kt4=bA(4) kt5=pers[3] kt6,7=LDS
//   refill:  kt0: bA<-slice4 (use @kt4, 4-phase lead)
//            kt4: bA<-slice0' (use @kt0 next step, 4-phase lead; issued
//                 BEFORE the epilogue stores -> no store-drain in the wait)
// ---------------------------------------------------------------------------
__global__ __launch_bounds__(512, 2) void lstm_kernel(
    const float* __restrict__ xp,            // [4096,1024] fp32, gates i|f|g|o
    const unsigned short* __restrict__ whhf, // packed bf16 fragments
    float* __restrict__ out) {               // [4096,50,256] fp32
  __shared__ unsigned short h_frag[2][8][64][8];  // [buf][kt][lane][j] 16 KB
  __shared__ unsigned short whh_lds[65536];       // kt-slices 6,7: 128 KB

  const int tid = threadIdx.x;
  const int wave = tid >> 6;
  const int lane = tid & 63;
  const int quad = lane >> 4;
  const int l16 = lane & 15;
  const int block_m = blockIdx.x * 16;
  const int ut0 = wave * 2;

  for (int i = tid; i < 2 * 8 * 64 * 8; i += 512)
    ((unsigned short*)h_frag)[i] = 0;

  // LDS-cache W_hh slices 6,7 (whhf shorts [196608, 262144), 128 KB)
  {
    const short8* s = (const short8*)(whhf + 196608);
    short8* d = (short8*)whh_lds;
    for (int i = tid; i < 8192; i += 512) d[i] = s[i];
  }

  // x_part in registers, C-fragment layout; i = g*2 + utl
  floatx4 xpreg[8];
#pragma unroll
  for (int i = 0; i < 8; ++i) {
    int g = i >> 1, utl = i & 1;
    int col = g * 256 + (ut0 + utl) * 16 + l16;
    floatx4 v;
#pragma unroll
    for (int r = 0; r < 4; ++r)
      v[r] = xp[(size_t)(block_m + quad * 4 + r) * 1024 + col];
    xpreg[i] = v;
  }

  float c[2][4] = {};

  // PERSISTENT register slices 1,2,3,5 (t-invariant; intentionally hoisted).
  short8 pers[4][8];
  {
    const unsigned short* p0 =
        whhf + ((size_t)((1 * 8 + wave) * 8) * 64 + lane) * 8;
    const unsigned short* p1 =
        whhf + ((size_t)((2 * 8 + wave) * 8) * 64 + lane) * 8;
    const unsigned short* p2 =
        whhf + ((size_t)((3 * 8 + wave) * 8) * 64 + lane) * 8;
    const unsigned short* p3 =
        whhf + ((size_t)((5 * 8 + wave) * 8) * 64 + lane) * 8;
#pragma unroll
    for (int i = 0; i < 8; ++i) {
      pers[0][i] = *(const short8*)(p0 + i * 512);
      pers[1][i] = *(const short8*)(p1 + i * 512);
      pers[2][i] = *(const short8*)(p2 + i * 512);
      pers[3][i] = *(const short8*)(p3 + i * 512);
    }
  }

  // Stream prologue: slice 0 for t=0 into the single rolling buffer.
  short8 bA[8];
  {
    const unsigned short* w0 =
        whhf + ((size_t)((0 * 8 + wave) * 8) * 64 + lane) * 8;
#pragma unroll
    for (int i = 0; i < 8; ++i) bA[i] = *(const short8*)(w0 + i * 512);
  }

  __syncthreads();

  const size_t orow = (size_t)TSTEPS * HID;
  int cur = 0;

#pragma unroll 1
  for (int t = 0; t < TSTEPS; ++t) {
    // launder: keep streamed B loads + LDS B reads inside the loop
    const unsigned short* wb = whhf;
    asm volatile("" : "+s"(wb));
    unsigned lofs = 0;
    asm volatile("" : "+v"(lofs));

    floatx4 acc[8];

    // rolling A-fragment (h) prefetch, depth 1, within-step only
    short8 aab[2];
    aab[0] = *(const short8*)&h_frag[cur][0][lane][0];

#pragma unroll
    for (int kt = 0; kt < 8; ++kt) {
      const short8 a = aab[kt & 1];
      if (kt < 7)  // next A-frag from LDS (cur buffer fully written)
        aab[(kt + 1) & 1] = *(const short8*)&h_frag[cur][kt + 1][lane][0];

      if (kt == 0) {
#pragma unroll
        for (int i = 0; i < 8; ++i)
          acc[i] = __builtin_amdgcn_mfma_f32_16x16x32_bf16(a, bA[i],
                                                           xpreg[i], 0, 0, 0);
        // refill bA <- slice 4 (consumed @kt4; WAR resolved by MFMA reads)
        const unsigned short* wbp =
            wb + ((size_t)((4 * 8 + wave) * 8) * 64 + lane) * 8;
#pragma unroll
        for (int i = 0; i < 8; ++i) bA[i] = *(const short8*)(wbp + i * 512);
      } else if (kt == 1) {
#pragma unroll
        for (int i = 0; i < 8; ++i)
          acc[i] = __builtin_amdgcn_mfma_f32_16x16x32_bf16(a, pers[0][i],
                                                           acc[i], 0, 0, 0);
      } else if (kt == 2) {
#pragma unroll
        for (int i = 0; i < 8; ++i)
          acc[i] = __builtin_amdgcn_mfma_f32_16x16x32_bf16(a, pers[1][i],
                                                           acc[i], 0, 0, 0);
      } else if (kt == 3) {
#pragma unroll
        for (int i = 0; i < 8; ++i)
          acc[i] = __builtin_amdgcn_mfma_f32_16x16x32_bf16(a, pers[2][i],
                                                           acc[i], 0, 0, 0);
      } else if (kt == 4) {
#pragma unroll
        for (int i = 0; i < 8; ++i)
          acc[i] = __builtin_amdgcn_mfma_f32_16x16x32_bf16(a, bA[i],
                                                           acc[i], 0, 0, 0);
        // refill bA <- next step's slice 0 (use @kt0', 4-phase lead,
        // issued ahead of this step's epilogue stores in the vmcnt FIFO)
        const unsigned short* wbp =
            wb + ((size_t)((0 * 8 + wave) * 8) * 64 + lane) * 8;
#pragma unroll
        for (int i = 0; i < 8; ++i) bA[i] = *(const short8*)(wbp + i * 512);
      } else if (kt == 5) {
#pragma unroll
        for (int i = 0; i < 8; ++i)
          acc[i] = __builtin_amdgcn_mfma_f32_16x16x32_bf16(a, pers[3][i],
                                                           acc[i], 0, 0, 0);
      } else {  // kt = 6,7: B from LDS (slices 6,7)
#pragma unroll
        for (int i = 0; i < 8; ++i) {
          const short8 bl = *(const short8*)&whh_lds[
              lofs + (size_t)((((kt - 6) * 8 + wave) * 8 + i) * 512) + lane * 8];
          acc[i] = __builtin_amdgcn_mfma_f32_16x16x32_bf16(a, bl, acc[i],
                                                           0, 0, 0);
        }
      }
    }

    const int nxt = cur ^ 1;
#pragma unroll
    for (int utl = 0; utl < 2; ++utl) {
      floatx4 gi = acc[0 + utl];
      floatx4 gf = acc[2 + utl];
      floatx4 gg = acc[4 + utl];
      floatx4 go = acc[6 + utl];
      const int u = (ut0 + utl) * 16 + l16;
      const int kt2 = u >> 5;
      const int lhi = ((u >> 3) & 3) << 4;
      const int j2 = u & 7;
#pragma unroll
      for (int r = 0; r < 4; ++r) {
        float iv = sigmf(gi[r]);
        float fv = sigmf(gf[r]);
        float gv = tanhf_(gg[r]);
        float ov = sigmf(go[r]);
        float cv = fmaf(fv, c[utl][r], iv * gv);
        c[utl][r] = cv;
        float hv = ov * tanhf_(cv);
        int mloc = quad * 4 + r;
        // non-temporal: don't let the 205 MB out-stream evict W_hh from L2
        __builtin_nontemporal_store(
            hv, &out[(size_t)(block_m + mloc) * orow + (size_t)t * HID + u]);
        h_frag[nxt][kt2][mloc | lhi][j2] = f2bf(hv);
      }
    }
    cur = nxt;
    lds_barrier();  // h_frag visibility only; vmcnt queue keeps flowing
  }
}

// ---------------------------------------------------------------------------
extern "C" void kernel_launch(void* const* d_in, const int* in_sizes, int n_in,
                              void* d_out, int out_size, void* d_ws, size_t ws_size,
                              hipStream_t stream) {
  const float* zs  = (const float*)d_in[0];
  const float* W1  = (const float*)d_in[1];
  const float* b1  = (const float*)d_in[2];
  const float* W2  = (const float*)d_in[3];
  const float* b2  = (const float*)d_in[4];
  const float* W3  = (const float*)d_in[5];
  const float* b3  = (const float*)d_in[6];
  const float* Wih = (const float*)d_in[7];
  const float* Whh = (const float*)d_in[8];
  const float* bih = (const float*)d_in[9];
  const float* bhh = (const float*)d_in[10];
  float* out = (float*)d_out;

  char* ws = (char*)d_ws;
  const size_t MB = 1024 * 1024;
  unsigned short* zs_h = (unsigned short*)(ws + 0 * MB);       // 2 MB
  unsigned short* zs_l = (unsigned short*)(ws + 2 * MB);       // 2 MB
  unsigned short* h1_h = (unsigned short*)(ws + 4 * MB);       // 4 MB
  unsigned short* h1_l = (unsigned short*)(ws + 8 * MB);       // 4 MB
  unsigned short* h2_h = (unsigned short*)(ws + 0 * MB);       // reuse zs (2 MB)
  unsigned short* h2_l = (unsigned short*)(ws + 2 * MB);       // reuse zs (2 MB)
  unsigned short* zb_h = (unsigned short*)(ws + 12 * MB);      // 1 MB
  unsigned short* zb_l = (unsigned short*)(ws + 13 * MB);      // 1 MB
  unsigned short* w1_h = (unsigned short*)(ws + 14 * MB);                 // 256 KB
  unsigned short* w1_l = (unsigned short*)(ws + 14 * MB + 256 * 1024);
  unsigned short* w2_h = (unsigned short*)(ws + 14 * MB + 512 * 1024);
  unsigned short* w2_l = (unsigned short*)(ws + 14 * MB + 768 * 1024);
  unsigned short* w3_h = (unsigned short*)(ws + 15 * MB);                 // 64 KB
  unsigned short* w3_l = (unsigned short*)(ws + 15 * MB + 64 * 1024);
  unsigned short* wi_h = (unsigned short*)(ws + 15 * MB + 128 * 1024);    // 256 KB
  unsigned short* wi_l = (unsigned short*)(ws + 15 * MB + 384 * 1024);
  float* xp            = (float*)(ws + 16 * MB);               // 16 MB
  unsigned short* whhf = (unsigned short*)(ws + 32 * MB);      // 512 KB

  // fp32 -> hi/lo bf16 splits (zs, W1, W2, W3, Wih) + W_hh fragment pack,
  // one fused launch (blocks [1440,1568) do the pack).
  split_all<<<1568, 256, 0, stream>>>(zs, zs_h, zs_l, W1, w1_h, w1_l,
                                      W2, w2_h, w2_l, W3, w3_h, w3_l,
                                      Wih, wi_h, wi_l, Whh, whhf);

  // MLP: h1 = relu(zs@W1^T+b1); h2 = relu(h1@W2^T+b2); zb = h2@W3^T+b3
  gemm_df<1, 1, 0><<<dim3(512 / 64, BATCH / 64), 256, 0, stream>>>(
      zs_h, zs_l, w1_h, w1_l, b1, nullptr, nullptr, h1_h, h1_l, BATCH, 512, 256);
  gemm_df<1, 1, 0><<<dim3(256 / 64, BATCH / 64), 256, 0, stream>>>(
      h1_h, h1_l, w2_h, w2_l, b2, nullptr, nullptr, h2_h, h2_l, BATCH, 256, 512);
  gemm_df<0, 1, 0><<<dim3(128 / 64, BATCH / 64), 256, 0, stream>>>(
      h2_h, h2_l, w3_h, w3_l, b3, nullptr, nullptr, zb_h, zb_l, BATCH, 128, 256);
  // xp = zb@Wih^T + b_ih + b_hh  (fp32 out)
  gemm_df<0, 0, 1><<<dim3(1024 / 64, BATCH / 64), 256, 0, stream>>>(
      zb_h, zb_l, wi_h, wi_l, bih, bhh, xp, nullptr, nullptr, BATCH, 1024, 128);

  lstm_kernel<<<BATCH / 16, 512, 0, stream>>>(xp, whhf, out);
}

// Round 7
// 358.027 us; speedup vs baseline: 1.8804x; 1.0697x over previous
//
#include <hip/hip_runtime.h>
#include <stdint.h>

// ---------------------------------------------------------------------------
// Predictor: MLP (256->512->256->128) -> LSTM(128 in, 256 hidden, T=50)
// v6: TWO launches total.
//   1) pack_all: all weights -> MFMA B-fragment layout (hi/lo split-bf16 for
//      W1,W2,W3,Wih; bf16 for W_hh).
//   2) lstm_fused: 256 blocks x 512 thr, 16 batch rows/block.
//      PROLOGUE (per block): zs -> split -> h1 -> h2 -> zb -> xpreg, the whole
//      MLP chain in-block. B operands read as fragments straight from L2
//      (pre-packed), A operands / stage outputs in LDS A-fragment layout
//      (same index math as the production h_frag write). Stage D's MFMA
//      C-layout IS xpreg's layout -> xp never exists in memory.
//      Accumulation order identical to the old gemm_df -> bitwise-identical
//      results.
//      MAIN LOOP: unchanged v5 (L2-stream-minimized W_hh: slices 1,2,3,5 in
//      persistent regs; 6,7 in LDS; 0,4 streamed via 1 rolling buffer with
//      4-phase cross-barrier prefetch; lgkm-only barriers; NT stores).
//   Rationale: non-lstm time was ~210 us across 5 rounds while real aux
//   kernel work is ~25 us -> launch/gap overhead dominates; collapse it.
//   (Resubmission: round-6 bench died to container-level infra failure, same
//    signature as round 1 which passed on identical resubmit. Full OOB/
//    aliasing/layout/barrier audit found no kernel-level fault. Unchanged.)
// ---------------------------------------------------------------------------

typedef short short8 __attribute__((ext_vector_type(8)));
typedef float floatx4 __attribute__((ext_vector_type(4)));

#define BATCH 4096
#define HID 256
#define TSTEPS 50

static __device__ __forceinline__ unsigned short f2bf(float x) {
  union { float f; unsigned int u; } v; v.f = x;
  unsigned int r = (v.u + 0x7fffu + ((v.u >> 16) & 1u)) >> 16;  // RNE
  return (unsigned short)r;
}
static __device__ __forceinline__ float bf2f(unsigned short h) {
  union { unsigned int u; float f; } v; v.u = ((unsigned int)h) << 16;
  return v.f;
}
static __device__ __forceinline__ float sigmf(float x) {
  return __builtin_amdgcn_rcpf(1.0f + __expf(-x));
}
static __device__ __forceinline__ float tanhf_(float x) {
  return 1.0f - 2.0f * __builtin_amdgcn_rcpf(__expf(2.0f * x) + 1.0f);
}

// lgkm-only barrier: LDS visibility without draining the vmcnt queue.
static __device__ __forceinline__ void lds_barrier() {
  __asm__ volatile("s_waitcnt lgkmcnt(0)\n\ts_barrier" ::: "memory");
}

// ---------------------------------------------------------------------------
// pack_all: weights -> B-fragment layout.
//   Fragment (nt,kt): lane holds B[n = nt*16 + (lane&15)][kt*32 + (lane>>4)*8
//   + j], j=0..7; stored at frag[(nt*NKT + kt)*64 + lane][8].
//   blocks [0,64):    W1  [512,256]  -> w1fh/w1fl   (NKT=8)
//   blocks [64,128):  W2  [256,512]  -> w2fh/w2fl   (NKT=16)
//   blocks [128,144): W3  [128,256]  -> w3fh/w3fl   (NKT=8)
//   blocks [144,208): Wih [1024,128] -> wifh/wifl   (NKT=4)
//   blocks [208,336): W_hh[1024,256] -> whhf, wave-interleaved layout
//                     idx = ((kt*8+w)*8+i)*64+lane, nt = (i>>1)*16+w*2+(i&1)
// ---------------------------------------------------------------------------
__global__ __launch_bounds__(256) void pack_all(
    const float* __restrict__ W1, const float* __restrict__ W2,
    const float* __restrict__ W3, const float* __restrict__ Wih,
    const float* __restrict__ Whh,
    unsigned short* __restrict__ w1fh, unsigned short* __restrict__ w1fl,
    unsigned short* __restrict__ w2fh, unsigned short* __restrict__ w2fl,
    unsigned short* __restrict__ w3fh, unsigned short* __restrict__ w3fl,
    unsigned short* __restrict__ wifh, unsigned short* __restrict__ wifl,
    unsigned short* __restrict__ whhf) {
  const int bid = blockIdx.x;
  const int tid = threadIdx.x;
  if (bid < 208) {  // hi/lo split-bf16 B-fragment packs
    const float* W; unsigned short *dh, *dl; int NKT, K, idx;
    if (bid < 64)       { W = W1;  dh = w1fh; dl = w1fl; NKT = 8;  K = 256; idx = bid * 256 + tid; }
    else if (bid < 128) { W = W2;  dh = w2fh; dl = w2fl; NKT = 16; K = 512; idx = (bid - 64) * 256 + tid; }
    else if (bid < 144) { W = W3;  dh = w3fh; dl = w3fl; NKT = 8;  K = 256; idx = (bid - 128) * 256 + tid; }
    else                { W = Wih; dh = wifh; dl = wifl; NKT = 4;  K = 128; idx = (bid - 144) * 256 + tid; }
    const int lane = idx & 63, f = idx >> 6;
    const int nt = f / NKT, kt = f - nt * NKT;
    const int n = nt * 16 + (lane & 15);
    const int k0 = kt * 32 + (lane >> 4) * 8;
    const float* src = W + (size_t)n * K + k0;
#pragma unroll
    for (int j = 0; j < 8; ++j) {
      float v = src[j];
      unsigned short hb = f2bf(v);
      dh[(size_t)idx * 8 + j] = hb;
      dl[(size_t)idx * 8 + j] = f2bf(v - bf2f(hb));
    }
  } else {  // W_hh pack (bf16), wave-interleaved
    const int idx = (bid - 208) * 256 + tid;
    const int lane = idx & 63;
    const int i = (idx >> 6) & 7;
    const int w = (idx >> 9) & 7;
    const int kt = idx >> 12;
    const int nt = (i >> 1) * 16 + w * 2 + (i & 1);
    const int n = nt * 16 + (lane & 15);
    const int k0 = kt * 32 + (lane >> 4) * 8;
    const float* src = Whh + (size_t)n * 256 + k0;
    unsigned short* dst = whhf + (size_t)idx * 8;
#pragma unroll
    for (int j = 0; j < 8; ++j) dst[j] = f2bf(src[j]);
  }
}

// ---------------------------------------------------------------------------
// One MLP stage (16 rows x 16*?: per-wave n-tile), split-bf16 MFMA, output
// written to LDS in A-fragment layout (same math as the h_frag write).
// ---------------------------------------------------------------------------
template <int NKT, int RELU>
static __device__ __forceinline__ void mlp_stage(
    const unsigned short (*ah)[64][8], const unsigned short (*al)[64][8],
    const unsigned short* __restrict__ bfh, const unsigned short* __restrict__ bfl,
    int nt, const float* __restrict__ bias,
    unsigned short (*oh)[64][8], unsigned short (*ol)[64][8],
    int lane, int quad, int l16) {
  floatx4 acc = {};
  const size_t base = ((size_t)(nt * NKT) * 64 + lane) * 8;
#pragma unroll
  for (int kt = 0; kt < NKT; ++kt) {
    short8 a_h = *(const short8*)&ah[kt][lane][0];
    short8 a_l = *(const short8*)&al[kt][lane][0];
    short8 b_h = *(const short8*)(bfh + base + kt * 512);
    short8 b_l = *(const short8*)(bfl + base + kt * 512);
    acc = __builtin_amdgcn_mfma_f32_16x16x32_bf16(a_l, b_h, acc, 0, 0, 0);
    acc = __builtin_amdgcn_mfma_f32_16x16x32_bf16(a_h, b_l, acc, 0, 0, 0);
    acc = __builtin_amdgcn_mfma_f32_16x16x32_bf16(a_h, b_h, acc, 0, 0, 0);
  }
  const int col = nt * 16 + l16;
  const float bj = bias[col];
  const int kt2 = col >> 5, lhi = ((col >> 3) & 3) << 4, j2 = col & 7;
#pragma unroll
  for (int r = 0; r < 4; ++r) {
    float v = acc[r] + bj;
    if (RELU) v = fmaxf(v, 0.f);
    unsigned short hb = f2bf(v);
    oh[kt2][(quad * 4 + r) | lhi][j2] = hb;
    ol[kt2][(quad * 4 + r) | lhi][j2] = f2bf(v - bf2f(hb));
  }
}

// ---------------------------------------------------------------------------
// Fused MLP + persistent LSTM. 256 blocks x 512 threads (8 waves), 16 rows.
// ---------------------------------------------------------------------------
__global__ __launch_bounds__(512, 2) void lstm_fused(
    const float* __restrict__ zs,             // [4096,256] fp32
    const float* __restrict__ b1, const float* __restrict__ b2,
    const float* __restrict__ b3,
    const float* __restrict__ bih, const float* __restrict__ bhh,
    const unsigned short* __restrict__ w1fh, const unsigned short* __restrict__ w1fl,
    const unsigned short* __restrict__ w2fh, const unsigned short* __restrict__ w2fl,
    const unsigned short* __restrict__ w3fh, const unsigned short* __restrict__ w3fl,
    const unsigned short* __restrict__ wifh, const unsigned short* __restrict__ wifl,
    const unsigned short* __restrict__ whhf,  // packed bf16 fragments
    float* __restrict__ out) {                // [4096,50,256] fp32
  __shared__ __align__(16) unsigned char smem[147456];
  // steady state: whh_lds [0,131072), h_frag [131072,147456)
  unsigned short* whh_lds = (unsigned short*)smem;
  unsigned short (*h_frag)[8][64][8] = (unsigned short(*)[8][64][8])(smem + 131072);
  // prologue aliases (inside the whh_lds region; dead before whh_lds fill)
  unsigned short (*zsh)[64][8] = (unsigned short(*)[64][8])(smem + 0);      // 8K
  unsigned short (*zsl)[64][8] = (unsigned short(*)[64][8])(smem + 8192);   // 8K
  unsigned short (*h1h)[64][8] = (unsigned short(*)[64][8])(smem + 16384);  // 16K
  unsigned short (*h1l)[64][8] = (unsigned short(*)[64][8])(smem + 32768);  // 16K
  unsigned short (*h2h)[64][8] = (unsigned short(*)[64][8])(smem + 49152);  // 8K
  unsigned short (*h2l)[64][8] = (unsigned short(*)[64][8])(smem + 57344);  // 8K
  unsigned short (*zbh)[64][8] = (unsigned short(*)[64][8])(smem + 65536);  // 4K
  unsigned short (*zbl)[64][8] = (unsigned short(*)[64][8])(smem + 69632);  // 4K

  const int tid = threadIdx.x;
  const int wave = tid >> 6;
  const int lane = tid & 63;
  const int quad = lane >> 4;
  const int l16 = lane & 15;
  const int block_m = blockIdx.x * 16;
  const int ut0 = wave * 2;

  // h_frag zero-init (disjoint from prologue region)
  for (int i = tid; i < 2 * 8 * 64 * 8; i += 512)
    ((unsigned short*)(smem + 131072))[i] = 0;

  // ---- MLP prologue ----
  // zs tile -> split-bf16 A-fragments. thread = (kt = tid>>6, lane)
  {
    const int kt = tid >> 6;  // 0..7
    const float* zrow =
        zs + (size_t)(block_m + l16) * 256 + kt * 32 + quad * 8;
    float4 z0 = *(const float4*)zrow;
    float4 z1 = *(const float4*)(zrow + 4);
    float zz[8] = {z0.x, z0.y, z0.z, z0.w, z1.x, z1.y, z1.z, z1.w};
#pragma unroll
    for (int j = 0; j < 8; ++j) {
      unsigned short hb = f2bf(zz[j]);
      zsh[kt][lane][j] = hb;
      zsl[kt][lane][j] = f2bf(zz[j] - bf2f(hb));
    }
  }
  lds_barrier();

  // Stage A: h1[16,512] = relu(zs @ W1^T + b1); wave w owns n-tiles 4w..4w+3
#pragma unroll
  for (int ntl = 0; ntl < 4; ++ntl)
    mlp_stage<8, 1>(zsh, zsl, w1fh, w1fl, wave * 4 + ntl, b1, h1h, h1l,
                    lane, quad, l16);
  lds_barrier();

  // Stage B: h2[16,256] = relu(h1 @ W2^T + b2); n-tiles 2w, 2w+1
#pragma unroll
  for (int ntl = 0; ntl < 2; ++ntl)
    mlp_stage<16, 1>(h1h, h1l, w2fh, w2fl, wave * 2 + ntl, b2, h2h, h2l,
                     lane, quad, l16);
  lds_barrier();

  // Stage C: zb[16,128] = h2 @ W3^T + b3; n-tile w
  mlp_stage<8, 0>(h2h, h2l, w3fh, w3fl, wave, b3, zbh, zbl, lane, quad, l16);
  lds_barrier();

  // Stage D: xpreg = zb @ Wih^T + bih + bhh  (MFMA C-layout == xpreg layout)
  floatx4 xpreg[8];
#pragma unroll
  for (int i = 0; i < 8; ++i) {
    const int nt = (i >> 1) * 16 + wave * 2 + (i & 1);
    floatx4 acc = {};
    const size_t base = ((size_t)(nt * 4) * 64 + lane) * 8;
#pragma unroll
    for (int kt = 0; kt < 4; ++kt) {
      short8 a_h = *(const short8*)&zbh[kt][lane][0];
      short8 a_l = *(const short8*)&zbl[kt][lane][0];
      short8 b_h = *(const short8*)(wifh + base + kt * 512);
      short8 b_l = *(const short8*)(wifl + base + kt * 512);
      acc = __builtin_amdgcn_mfma_f32_16x16x32_bf16(a_l, b_h, acc, 0, 0, 0);
      acc = __builtin_amdgcn_mfma_f32_16x16x32_bf16(a_h, b_l, acc, 0, 0, 0);
      acc = __builtin_amdgcn_mfma_f32_16x16x32_bf16(a_h, b_h, acc, 0, 0, 0);
    }
    const int col = nt * 16 + l16;
    const float bj = bih[col] + bhh[col];
#pragma unroll
    for (int r = 0; r < 4; ++r) xpreg[i][r] = acc[r] + bj;
  }
  lds_barrier();  // zb reads complete before whh_lds overwrites the region

  // ---- LSTM setup (unchanged v5) ----
  // LDS-cache W_hh slices 6,7 (whhf shorts [196608, 262144), 128 KB)
  {
    const short8* s = (const short8*)(whhf + 196608);
    short8* d = (short8*)whh_lds;
    for (int i = tid; i < 8192; i += 512) d[i] = s[i];
  }

  float c[2][4] = {};

  // PERSISTENT register slices 1,2,3,5 (t-invariant; intentionally hoisted).
  short8 pers[4][8];
  {
    const unsigned short* p0 = whhf + ((size_t)((1 * 8 + wave) * 8) * 64 + lane) * 8;
    const unsigned short* p1 = whhf + ((size_t)((2 * 8 + wave) * 8) * 64 + lane) * 8;
    const unsigned short* p2 = whhf + ((size_t)((3 * 8 + wave) * 8) * 64 + lane) * 8;
    const unsigned short* p3 = whhf + ((size_t)((5 * 8 + wave) * 8) * 64 + lane) * 8;
#pragma unroll
    for (int i = 0; i < 8; ++i) {
      pers[0][i] = *(const short8*)(p0 + i * 512);
      pers[1][i] = *(const short8*)(p1 + i * 512);
      pers[2][i] = *(const short8*)(p2 + i * 512);
      pers[3][i] = *(const short8*)(p3 + i * 512);
    }
  }

  // Stream prologue: slice 0 for t=0 into the single rolling buffer.
  short8 bA[8];
  {
    const unsigned short* w0 = whhf + ((size_t)((0 * 8 + wave) * 8) * 64 + lane) * 8;
#pragma unroll
    for (int i = 0; i < 8; ++i) bA[i] = *(const short8*)(w0 + i * 512);
  }

  __syncthreads();

  const size_t orow = (size_t)TSTEPS * HID;
  int cur = 0;

#pragma unroll 1
  for (int t = 0; t < TSTEPS; ++t) {
    // launder: keep streamed B loads + LDS B reads inside the loop
    const unsigned short* wb = whhf;
    asm volatile("" : "+s"(wb));
    unsigned lofs = 0;
    asm volatile("" : "+v"(lofs));

    floatx4 acc[8];

    // rolling A-fragment (h) prefetch, depth 1, within-step only
    short8 aab[2];
    aab[0] = *(const short8*)&h_frag[cur][0][lane][0];

#pragma unroll
    for (int kt = 0; kt < 8; ++kt) {
      const short8 a = aab[kt & 1];
      if (kt < 7)  // next A-frag from LDS (cur buffer fully written)
        aab[(kt + 1) & 1] = *(const short8*)&h_frag[cur][kt + 1][lane][0];

      if (kt == 0) {
#pragma unroll
        for (int i = 0; i < 8; ++i)
          acc[i] = __builtin_amdgcn_mfma_f32_16x16x32_bf16(a, bA[i],
                                                           xpreg[i], 0, 0, 0);
        // refill bA <- slice 4 (consumed @kt4; WAR resolved by MFMA reads)
        const unsigned short* wbp =
            wb + ((size_t)((4 * 8 + wave) * 8) * 64 + lane) * 8;
#pragma unroll
        for (int i = 0; i < 8; ++i) bA[i] = *(const short8*)(wbp + i * 512);
      } else if (kt == 1) {
#pragma unroll
        for (int i = 0; i < 8; ++i)
          acc[i] = __builtin_amdgcn_mfma_f32_16x16x32_bf16(a, pers[0][i],
                                                           acc[i], 0, 0, 0);
      } else if (kt == 2) {
#pragma unroll
        for (int i = 0; i < 8; ++i)
          acc[i] = __builtin_amdgcn_mfma_f32_16x16x32_bf16(a, pers[1][i],
                                                           acc[i], 0, 0, 0);
      } else if (kt == 3) {
#pragma unroll
        for (int i = 0; i < 8; ++i)
          acc[i] = __builtin_amdgcn_mfma_f32_16x16x32_bf16(a, pers[2][i],
                                                           acc[i], 0, 0, 0);
      } else if (kt == 4) {
#pragma unroll
        for (int i = 0; i < 8; ++i)
          acc[i] = __builtin_amdgcn_mfma_f32_16x16x32_bf16(a, bA[i],
                                                           acc[i], 0, 0, 0);
        // refill bA <- next step's slice 0 (use @kt0', 4-phase lead,
        // issued ahead of this step's epilogue stores in the vmcnt FIFO)
        const unsigned short* wbp =
            wb + ((size_t)((0 * 8 + wave) * 8) * 64 + lane) * 8;
#pragma unroll
        for (int i = 0; i < 8; ++i) bA[i] = *(const short8*)(wbp + i * 512);
      } else if (kt == 5) {
#pragma unroll
        for (int i = 0; i < 8; ++i)
          acc[i] = __builtin_amdgcn_mfma_f32_16x16x32_bf16(a, pers[3][i],
                                                           acc[i], 0, 0, 0);
      } else {  // kt = 6,7: B from LDS (slices 6,7)
#pragma unroll
        for (int i = 0; i < 8; ++i) {
          const short8 bl = *(const short8*)&whh_lds[
              lofs + (size_t)((((kt - 6) * 8 + wave) * 8 + i) * 512) + lane * 8];
          acc[i] = __builtin_amdgcn_mfma_f32_16x16x32_bf16(a, bl, acc[i],
                                                           0, 0, 0);
        }
      }
    }

    const int nxt = cur ^ 1;
#pragma unroll
    for (int utl = 0; utl < 2; ++utl) {
      floatx4 gi = acc[0 + utl];
      floatx4 gf = acc[2 + utl];
      floatx4 gg = acc[4 + utl];
      floatx4 go = acc[6 + utl];
      const int u = (ut0 + utl) * 16 + l16;
      const int kt2 = u >> 5;
      const int lhi = ((u >> 3) & 3) << 4;
      const int j2 = u & 7;
#pragma unroll
      for (int r = 0; r < 4; ++r) {
        float iv = sigmf(gi[r]);
        float fv = sigmf(gf[r]);
        float gv = tanhf_(gg[r]);
        float ov = sigmf(go[r]);
        float cv = fmaf(fv, c[utl][r], iv * gv);
        c[utl][r] = cv;
        float hv = ov * tanhf_(cv);
        int mloc = quad * 4 + r;
        // non-temporal: don't let the 205 MB out-stream evict W_hh from L2
        __builtin_nontemporal_store(
            hv, &out[(size_t)(block_m + mloc) * orow + (size_t)t * HID + u]);
        h_frag[nxt][kt2][mloc | lhi][j2] = f2bf(hv);
      }
    }
    cur = nxt;
    lds_barrier();  // h_frag visibility only; vmcnt queue keeps flowing
  }
}

// ---------------------------------------------------------------------------
extern "C" void kernel_launch(void* const* d_in, const int* in_sizes, int n_in,
                              void* d_out, int out_size, void* d_ws, size_t ws_size,
                              hipStream_t stream) {
  const float* zs  = (const float*)d_in[0];
  const float* W1  = (const float*)d_in[1];
  const float* b1  = (const float*)d_in[2];
  const float* W2  = (const float*)d_in[3];
  const float* b2  = (const float*)d_in[4];
  const float* W3  = (const float*)d_in[5];
  const float* b3  = (const float*)d_in[6];
  const float* Wih = (const float*)d_in[7];
  const float* Whh = (const float*)d_in[8];
  const float* bih = (const float*)d_in[9];
  const float* bhh = (const float*)d_in[10];
  float* out = (float*)d_out;

  char* ws = (char*)d_ws;
  const size_t KB = 1024;
  unsigned short* w1fh = (unsigned short*)(ws + 0);            // 256 KB
  unsigned short* w1fl = (unsigned short*)(ws + 256 * KB);     // 256 KB
  unsigned short* w2fh = (unsigned short*)(ws + 512 * KB);     // 256 KB
  unsigned short* w2fl = (unsigned short*)(ws + 768 * KB);     // 256 KB
  unsigned short* w3fh = (unsigned short*)(ws + 1024 * KB);    // 64 KB
  unsigned short* w3fl = (unsigned short*)(ws + 1088 * KB);    // 64 KB
  unsigned short* wifh = (unsigned short*)(ws + 1152 * KB);    // 256 KB
  unsigned short* wifl = (unsigned short*)(ws + 1408 * KB);    // 256 KB
  unsigned short* whhf = (unsigned short*)(ws + 2048 * KB);    // 512 KB

  // 1) all weights -> fragment layouts (one small launch)
  pack_all<<<336, 256, 0, stream>>>(W1, W2, W3, Wih, Whh,
                                    w1fh, w1fl, w2fh, w2fl, w3fh, w3fl,
                                    wifh, wifl, whhf);

  // 2) fused MLP prologue + persistent LSTM
  lstm_fused<<<BATCH / 16, 512, 0, stream>>>(
      zs, b1, b2, b3, bih, bhh, w1fh, w1fl, w2fh, w2fl, w3fh, w3fl,
      wifh, wifl, whhf, out);
}

// Round 8
// 348.918 us; speedup vs baseline: 1.9295x; 1.0261x over previous
//
#include <hip/hip_runtime.h>
#include <stdint.h>

// ---------------------------------------------------------------------------
// Predictor: MLP (256->512->256->128) -> LSTM(128 in, 256 hidden, T=50)
// v7: TWO launches (pack_all + lstm_fused).
//   lstm_fused: 256 blocks x 512 thr, 16 batch rows/block.
//   PROLOGUE: in-block MLP chain (zs->split->h1->h2->zb->xpreg), B operands
//   pre-packed fragments from L2, stage outputs in LDS A-fragment layout.
//   pers/bA W_hh register loads are issued BEFORE the stage-D barrier so
//   their latency hides under the barrier + whh_lds fill.
//   MAIN LOOP (v7): W_hh residency
//     slices 1,2,3,4,5 -> PERSISTENT REGISTERS (160 VGPR/wave)
//     slices 6,7       -> LDS (128 KB, ds_read_b128 at consume)
//     slice  0         -> streamed from L2, ONE rolling buffer bA,
//                         refill @kt1 <- slice0' (7-phase cross-barrier
//                         issue-to-use lead, ahead of epilogue NT stores)
//   L2 stream: 512 (v2) -> 384 -> 192 -> 128 -> 64 KB/CU/step.
//   Identical arithmetic order to v5/v6 -> bitwise-identical output.
// ---------------------------------------------------------------------------

typedef short short8 __attribute__((ext_vector_type(8)));
typedef float floatx4 __attribute__((ext_vector_type(4)));

#define BATCH 4096
#define HID 256
#define TSTEPS 50

static __device__ __forceinline__ unsigned short f2bf(float x) {
  union { float f; unsigned int u; } v; v.f = x;
  unsigned int r = (v.u + 0x7fffu + ((v.u >> 16) & 1u)) >> 16;  // RNE
  return (unsigned short)r;
}
static __device__ __forceinline__ float bf2f(unsigned short h) {
  union { unsigned int u; float f; } v; v.u = ((unsigned int)h) << 16;
  return v.f;
}
static __device__ __forceinline__ float sigmf(float x) {
  return __builtin_amdgcn_rcpf(1.0f + __expf(-x));
}
static __device__ __forceinline__ float tanhf_(float x) {
  return 1.0f - 2.0f * __builtin_amdgcn_rcpf(__expf(2.0f * x) + 1.0f);
}

// lgkm-only barrier: LDS visibility without draining the vmcnt queue.
static __device__ __forceinline__ void lds_barrier() {
  __asm__ volatile("s_waitcnt lgkmcnt(0)\n\ts_barrier" ::: "memory");
}

// ---------------------------------------------------------------------------
// pack_all: weights -> B-fragment layout.
//   Fragment (nt,kt): lane holds B[n = nt*16 + (lane&15)][kt*32 + (lane>>4)*8
//   + j], j=0..7; stored at frag[(nt*NKT + kt)*64 + lane][8].
//   blocks [0,64):    W1  [512,256]  -> w1fh/w1fl   (NKT=8)
//   blocks [64,128):  W2  [256,512]  -> w2fh/w2fl   (NKT=16)
//   blocks [128,144): W3  [128,256]  -> w3fh/w3fl   (NKT=8)
//   blocks [144,208): Wih [1024,128] -> wifh/wifl   (NKT=4)
//   blocks [208,336): W_hh[1024,256] -> whhf, wave-interleaved layout
//                     idx = ((kt*8+w)*8+i)*64+lane, nt = (i>>1)*16+w*2+(i&1)
// ---------------------------------------------------------------------------
__global__ __launch_bounds__(256) void pack_all(
    const float* __restrict__ W1, const float* __restrict__ W2,
    const float* __restrict__ W3, const float* __restrict__ Wih,
    const float* __restrict__ Whh,
    unsigned short* __restrict__ w1fh, unsigned short* __restrict__ w1fl,
    unsigned short* __restrict__ w2fh, unsigned short* __restrict__ w2fl,
    unsigned short* __restrict__ w3fh, unsigned short* __restrict__ w3fl,
    unsigned short* __restrict__ wifh, unsigned short* __restrict__ wifl,
    unsigned short* __restrict__ whhf) {
  const int bid = blockIdx.x;
  const int tid = threadIdx.x;
  if (bid < 208) {  // hi/lo split-bf16 B-fragment packs
    const float* W; unsigned short *dh, *dl; int NKT, K, idx;
    if (bid < 64)       { W = W1;  dh = w1fh; dl = w1fl; NKT = 8;  K = 256; idx = bid * 256 + tid; }
    else if (bid < 128) { W = W2;  dh = w2fh; dl = w2fl; NKT = 16; K = 512; idx = (bid - 64) * 256 + tid; }
    else if (bid < 144) { W = W3;  dh = w3fh; dl = w3fl; NKT = 8;  K = 256; idx = (bid - 128) * 256 + tid; }
    else                { W = Wih; dh = wifh; dl = wifl; NKT = 4;  K = 128; idx = (bid - 144) * 256 + tid; }
    const int lane = idx & 63, f = idx >> 6;
    const int nt = f / NKT, kt = f - nt * NKT;
    const int n = nt * 16 + (lane & 15);
    const int k0 = kt * 32 + (lane >> 4) * 8;
    const float* src = W + (size_t)n * K + k0;
#pragma unroll
    for (int j = 0; j < 8; ++j) {
      float v = src[j];
      unsigned short hb = f2bf(v);
      dh[(size_t)idx * 8 + j] = hb;
      dl[(size_t)idx * 8 + j] = f2bf(v - bf2f(hb));
    }
  } else {  // W_hh pack (bf16), wave-interleaved
    const int idx = (bid - 208) * 256 + tid;
    const int lane = idx & 63;
    const int i = (idx >> 6) & 7;
    const int w = (idx >> 9) & 7;
    const int kt = idx >> 12;
    const int nt = (i >> 1) * 16 + w * 2 + (i & 1);
    const int n = nt * 16 + (lane & 15);
    const int k0 = kt * 32 + (lane >> 4) * 8;
    const float* src = Whh + (size_t)n * 256 + k0;
    unsigned short* dst = whhf + (size_t)idx * 8;
#pragma unroll
    for (int j = 0; j < 8; ++j) dst[j] = f2bf(src[j]);
  }
}

// ---------------------------------------------------------------------------
// One MLP stage (16 rows x 16*?: per-wave n-tile), split-bf16 MFMA, output
// written to LDS in A-fragment layout (same math as the h_frag write).
// ---------------------------------------------------------------------------
template <int NKT, int RELU>
static __device__ __forceinline__ void mlp_stage(
    const unsigned short (*ah)[64][8], const unsigned short (*al)[64][8],
    const unsigned short* __restrict__ bfh, const unsigned short* __restrict__ bfl,
    int nt, const float* __restrict__ bias,
    unsigned short (*oh)[64][8], unsigned short (*ol)[64][8],
    int lane, int quad, int l16) {
  floatx4 acc = {};
  const size_t base = ((size_t)(nt * NKT) * 64 + lane) * 8;
#pragma unroll
  for (int kt = 0; kt < NKT; ++kt) {
    short8 a_h = *(const short8*)&ah[kt][lane][0];
    short8 a_l = *(const short8*)&al[kt][lane][0];
    short8 b_h = *(const short8*)(bfh + base + kt * 512);
    short8 b_l = *(const short8*)(bfl + base + kt * 512);
    acc = __builtin_amdgcn_mfma_f32_16x16x32_bf16(a_l, b_h, acc, 0, 0, 0);
    acc = __builtin_amdgcn_mfma_f32_16x16x32_bf16(a_h, b_l, acc, 0, 0, 0);
    acc = __builtin_amdgcn_mfma_f32_16x16x32_bf16(a_h, b_h, acc, 0, 0, 0);
  }
  const int col = nt * 16 + l16;
  const float bj = bias[col];
  const int kt2 = col >> 5, lhi = ((col >> 3) & 3) << 4, j2 = col & 7;
#pragma unroll
  for (int r = 0; r < 4; ++r) {
    float v = acc[r] + bj;
    if (RELU) v = fmaxf(v, 0.f);
    unsigned short hb = f2bf(v);
    oh[kt2][(quad * 4 + r) | lhi][j2] = hb;
    ol[kt2][(quad * 4 + r) | lhi][j2] = f2bf(v - bf2f(hb));
  }
}

// ---------------------------------------------------------------------------
// Fused MLP + persistent LSTM. 256 blocks x 512 threads (8 waves), 16 rows.
// ---------------------------------------------------------------------------
__global__ __launch_bounds__(512, 2) void lstm_fused(
    const float* __restrict__ zs,             // [4096,256] fp32
    const float* __restrict__ b1, const float* __restrict__ b2,
    const float* __restrict__ b3,
    const float* __restrict__ bih, const float* __restrict__ bhh,
    const unsigned short* __restrict__ w1fh, const unsigned short* __restrict__ w1fl,
    const unsigned short* __restrict__ w2fh, const unsigned short* __restrict__ w2fl,
    const unsigned short* __restrict__ w3fh, const unsigned short* __restrict__ w3fl,
    const unsigned short* __restrict__ wifh, const unsigned short* __restrict__ wifl,
    const unsigned short* __restrict__ whhf,  // packed bf16 fragments
    float* __restrict__ out) {                // [4096,50,256] fp32
  __shared__ __align__(16) unsigned char smem[147456];
  // steady state: whh_lds [0,131072), h_frag [131072,147456)
  unsigned short* whh_lds = (unsigned short*)smem;
  unsigned short (*h_frag)[8][64][8] = (unsigned short(*)[8][64][8])(smem + 131072);
  // prologue aliases (inside the whh_lds region; dead before whh_lds fill)
  unsigned short (*zsh)[64][8] = (unsigned short(*)[64][8])(smem + 0);      // 8K
  unsigned short (*zsl)[64][8] = (unsigned short(*)[64][8])(smem + 8192);   // 8K
  unsigned short (*h1h)[64][8] = (unsigned short(*)[64][8])(smem + 16384);  // 16K
  unsigned short (*h1l)[64][8] = (unsigned short(*)[64][8])(smem + 32768);  // 16K
  unsigned short (*h2h)[64][8] = (unsigned short(*)[64][8])(smem + 49152);  // 8K
  unsigned short (*h2l)[64][8] = (unsigned short(*)[64][8])(smem + 57344);  // 8K
  unsigned short (*zbh)[64][8] = (unsigned short(*)[64][8])(smem + 65536);  // 4K
  unsigned short (*zbl)[64][8] = (unsigned short(*)[64][8])(smem + 69632);  // 4K

  const int tid = threadIdx.x;
  const int wave = tid >> 6;
  const int lane = tid & 63;
  const int quad = lane >> 4;
  const int l16 = lane & 15;
  const int block_m = blockIdx.x * 16;
  const int ut0 = wave * 2;

  // h_frag zero-init (disjoint from prologue region)
  for (int i = tid; i < 2 * 8 * 64 * 8; i += 512)
    ((unsigned short*)(smem + 131072))[i] = 0;

  // ---- MLP prologue ----
  // zs tile -> split-bf16 A-fragments. thread = (kt = tid>>6, lane)
  {
    const int kt = tid >> 6;  // 0..7
    const float* zrow =
        zs + (size_t)(block_m + l16) * 256 + kt * 32 + quad * 8;
    float4 z0 = *(const float4*)zrow;
    float4 z1 = *(const float4*)(zrow + 4);
    float zz[8] = {z0.x, z0.y, z0.z, z0.w, z1.x, z1.y, z1.z, z1.w};
#pragma unroll
    for (int j = 0; j < 8; ++j) {
      unsigned short hb = f2bf(zz[j]);
      zsh[kt][lane][j] = hb;
      zsl[kt][lane][j] = f2bf(zz[j] - bf2f(hb));
    }
  }
  lds_barrier();

  // Stage A: h1[16,512] = relu(zs @ W1^T + b1); wave w owns n-tiles 4w..4w+3
#pragma unroll
  for (int ntl = 0; ntl < 4; ++ntl)
    mlp_stage<8, 1>(zsh, zsl, w1fh, w1fl, wave * 4 + ntl, b1, h1h, h1l,
                    lane, quad, l16);
  lds_barrier();

  // Stage B: h2[16,256] = relu(h1 @ W2^T + b2); n-tiles 2w, 2w+1
#pragma unroll
  for (int ntl = 0; ntl < 2; ++ntl)
    mlp_stage<16, 1>(h1h, h1l, w2fh, w2fl, wave * 2 + ntl, b2, h2h, h2l,
                     lane, quad, l16);
  lds_barrier();

  // Stage C: zb[16,128] = h2 @ W3^T + b3; n-tile w
  mlp_stage<8, 0>(h2h, h2l, w3fh, w3fl, wave, b3, zbh, zbl, lane, quad, l16);
  lds_barrier();

  // Stage D: xpreg = zb @ Wih^T + bih + bhh  (MFMA C-layout == xpreg layout)
  floatx4 xpreg[8];
#pragma unroll
  for (int i = 0; i < 8; ++i) {
    const int nt = (i >> 1) * 16 + wave * 2 + (i & 1);
    floatx4 acc = {};
    const size_t base = ((size_t)(nt * 4) * 64 + lane) * 8;
#pragma unroll
    for (int kt = 0; kt < 4; ++kt) {
      short8 a_h = *(const short8*)&zbh[kt][lane][0];
      short8 a_l = *(const short8*)&zbl[kt][lane][0];
      short8 b_h = *(const short8*)(wifh + base + kt * 512);
      short8 b_l = *(const short8*)(wifl + base + kt * 512);
      acc = __builtin_amdgcn_mfma_f32_16x16x32_bf16(a_l, b_h, acc, 0, 0, 0);
      acc = __builtin_amdgcn_mfma_f32_16x16x32_bf16(a_h, b_l, acc, 0, 0, 0);
      acc = __builtin_amdgcn_mfma_f32_16x16x32_bf16(a_h, b_h, acc, 0, 0, 0);
    }
    const int col = nt * 16 + l16;
    const float bj = bih[col] + bhh[col];
#pragma unroll
    for (int r = 0; r < 4; ++r) xpreg[i][r] = acc[r] + bj;
  }

  // PERSISTENT register slices 1,2,3,4,5 + stream buffer (slice 0):
  // issued HERE (before the stage-D barrier + whh_lds fill) so their L2
  // latency hides under the barrier drain and the 128 KB LDS fill.
  short8 pers[5][8];
  short8 bA[8];
  {
#pragma unroll
    for (int sl = 0; sl < 5; ++sl) {
      const unsigned short* p =
          whhf + ((size_t)(((sl + 1) * 8 + wave) * 8) * 64 + lane) * 8;
#pragma unroll
      for (int i = 0; i < 8; ++i) pers[sl][i] = *(const short8*)(p + i * 512);
    }
    const unsigned short* w0 =
        whhf + ((size_t)((0 * 8 + wave) * 8) * 64 + lane) * 8;
#pragma unroll
    for (int i = 0; i < 8; ++i) bA[i] = *(const short8*)(w0 + i * 512);
  }

  lds_barrier();  // zb reads complete before whh_lds overwrites the region

  // ---- LSTM setup ----
  // LDS-cache W_hh slices 6,7 (whhf shorts [196608, 262144), 128 KB)
  {
    const short8* s = (const short8*)(whhf + 196608);
    short8* d = (short8*)whh_lds;
    for (int i = tid; i < 8192; i += 512) d[i] = s[i];
  }

  float c[2][4] = {};

  __syncthreads();

  const size_t orow = (size_t)TSTEPS * HID;
  int cur = 0;

#pragma unroll 1
  for (int t = 0; t < TSTEPS; ++t) {
    // launder: keep streamed B loads + LDS B reads inside the loop
    const unsigned short* wb = whhf;
    asm volatile("" : "+s"(wb));
    unsigned lofs = 0;
    asm volatile("" : "+v"(lofs));

    floatx4 acc[8];

    // rolling A-fragment (h) prefetch, depth 1, within-step only
    short8 aab[2];
    aab[0] = *(const short8*)&h_frag[cur][0][lane][0];

#pragma unroll
    for (int kt = 0; kt < 8; ++kt) {
      const short8 a = aab[kt & 1];
      if (kt < 7)  // next A-frag from LDS (cur buffer fully written)
        aab[(kt + 1) & 1] = *(const short8*)&h_frag[cur][kt + 1][lane][0];

      if (kt == 0) {
#pragma unroll
        for (int i = 0; i < 8; ++i)
          acc[i] = __builtin_amdgcn_mfma_f32_16x16x32_bf16(a, bA[i],
                                                           xpreg[i], 0, 0, 0);
      } else if (kt == 1) {
#pragma unroll
        for (int i = 0; i < 8; ++i)
          acc[i] = __builtin_amdgcn_mfma_f32_16x16x32_bf16(a, pers[0][i],
                                                           acc[i], 0, 0, 0);
        // refill bA <- next step's slice 0 (t-invariant address). 7-phase
        // issue-to-use lead (kt1 of t -> kt0 of t+1), issued ahead of the
        // epilogue's NT stores in the vmcnt FIFO. WAR on bA resolved by
        // kt0's MFMA operand reads above.
        const unsigned short* wbp =
            wb + ((size_t)((0 * 8 + wave) * 8) * 64 + lane) * 8;
#pragma unroll
        for (int i = 0; i < 8; ++i) bA[i] = *(const short8*)(wbp + i * 512);
      } else if (kt == 2) {
#pragma unroll
        for (int i = 0; i < 8; ++i)
          acc[i] = __builtin_amdgcn_mfma_f32_16x16x32_bf16(a, pers[1][i],
                                                           acc[i], 0, 0, 0);
      } else if (kt == 3) {
#pragma unroll
        for (int i = 0; i < 8; ++i)
          acc[i] = __builtin_amdgcn_mfma_f32_16x16x32_bf16(a, pers[2][i],
                                                           acc[i], 0, 0, 0);
      } else if (kt == 4) {
#pragma unroll
        for (int i = 0; i < 8; ++i)
          acc[i] = __builtin_amdgcn_mfma_f32_16x16x32_bf16(a, pers[3][i],
                                                           acc[i], 0, 0, 0);
      } else if (kt == 5) {
#pragma unroll
        for (int i = 0; i < 8; ++i)
          acc[i] = __builtin_amdgcn_mfma_f32_16x16x32_bf16(a, pers[4][i],
                                                           acc[i], 0, 0, 0);
      } else {  // kt = 6,7: B from LDS (slices 6,7)
#pragma unroll
        for (int i = 0; i < 8; ++i) {
          const short8 bl = *(const short8*)&whh_lds[
              lofs + (size_t)((((kt - 6) * 8 + wave) * 8 + i) * 512) + lane * 8];
          acc[i] = __builtin_amdgcn_mfma_f32_16x16x32_bf16(a, bl, acc[i],
                                                           0, 0, 0);
        }
      }
    }

    const int nxt = cur ^ 1;
#pragma unroll
    for (int utl = 0; utl < 2; ++utl) {
      floatx4 gi = acc[0 + utl];
      floatx4 gf = acc[2 + utl];
      floatx4 gg = acc[4 + utl];
      floatx4 go = acc[6 + utl];
      const int u = (ut0 + utl) * 16 + l16;
      const int kt2 = u >> 5;
      const int lhi = ((u >> 3) & 3) << 4;
      const int j2 = u & 7;
#pragma unroll
      for (int r = 0; r < 4; ++r) {
        float iv = sigmf(gi[r]);
        float fv = sigmf(gf[r]);
        float gv = tanhf_(gg[r]);
        float ov = sigmf(go[r]);
        float cv = fmaf(fv, c[utl][r], iv * gv);
        c[utl][r] = cv;
        float hv = ov * tanhf_(cv);
        int mloc = quad * 4 + r;
        // non-temporal: don't let the 205 MB out-stream evict W_hh from L2
        __builtin_nontemporal_store(
            hv, &out[(size_t)(block_m + mloc) * orow + (size_t)t * HID + u]);
        h_frag[nxt][kt2][mloc | lhi][j2] = f2bf(hv);
      }
    }
    cur = nxt;
    lds_barrier();  // h_frag visibility only; vmcnt queue keeps flowing
  }
}

// ---------------------------------------------------------------------------
extern "C" void kernel_launch(void* const* d_in, const int* in_sizes, int n_in,
                              void* d_out, int out_size, void* d_ws, size_t ws_size,
                              hipStream_t stream) {
  const float* zs  = (const float*)d_in[0];
  const float* W1  = (const float*)d_in[1];
  const float* b1  = (const float*)d_in[2];
  const float* W2  = (const float*)d_in[3];
  const float* b2  = (const float*)d_in[4];
  const float* W3  = (const float*)d_in[5];
  const float* b3  = (const float*)d_in[6];
  const float* Wih = (const float*)d_in[7];
  const float* Whh = (const float*)d_in[8];
  const float* bih = (const float*)d_in[9];
  const float* bhh = (const float*)d_in[10];
  float* out = (float*)d_out;

  char* ws = (char*)d_ws;
  const size_t KB = 1024;
  unsigned short* w1fh = (unsigned short*)(ws + 0);            // 256 KB
  unsigned short* w1fl = (unsigned short*)(ws + 256 * KB);     // 256 KB
  unsigned short* w2fh = (unsigned short*)(ws + 512 * KB);     // 256 KB
  unsigned short* w2fl = (unsigned short*)(ws + 768 * KB);     // 256 KB
  unsigned short* w3fh = (unsigned short*)(ws + 1024 * KB);    // 64 KB
  unsigned short* w3fl = (unsigned short*)(ws + 1088 * KB);    // 64 KB
  unsigned short* wifh = (unsigned short*)(ws + 1152 * KB);    // 256 KB
  unsigned short* wifl = (unsigned short*)(ws + 1408 * KB);    // 256 KB
  unsigned short* whhf = (unsigned short*)(ws + 2048 * KB);    // 512 KB

  // 1) all weights -> fragment layouts (one small launch)
  pack_all<<<336, 256, 0, stream>>>(W1, W2, W3, Wih, Whh,
                                    w1fh, w1fl, w2fh, w2fl, w3fh, w3fl,
                                    wifh, wifl, whhf);

  // 2) fused MLP prologue + persistent LSTM
  lstm_fused<<<BATCH / 16, 512, 0, stream>>>(
      zs, b1, b2, b3, bih, bhh, w1fh, w1fl, w2fh, w2fl, w3fh, w3fl,
      wifh, wifl, whhf, out);
}